// Round 14
// baseline (291.544 us; speedup 1.0000x reference)
//
#include <hip/hip_runtime.h>
#include <math.h>

#define BB 4
#define TT 2048
#define VV 1024
#define CC 256
#define MR (BB*TT)   // 8192 rows

using short8  = __attribute__((ext_vector_type(8))) short;
using ushort8 = __attribute__((ext_vector_type(8))) unsigned short;
using f32x4   = __attribute__((ext_vector_type(4))) float;

__device__ __forceinline__ float bs2f(unsigned short s) {
    return __uint_as_float(((unsigned int)s) << 16);
}
__device__ __forceinline__ unsigned short f2bs(float f) {
    unsigned int u = __float_as_uint(f);
    u += 0x7fffu + ((u >> 16) & 1u);          // round-to-nearest-even
    return (unsigned short)(u >> 16);
}
__device__ __forceinline__ void gl_lds16(const void* g, void* l) {
    __builtin_amdgcn_global_load_lds(
        (const __attribute__((address_space(1))) unsigned int*)g,
        (__attribute__((address_space(3))) unsigned int*)l, 16, 0, 0);
}
__device__ __forceinline__ float sigm(float x) { return 1.f / (1.f + expf(-x)); }
// Abramowitz-Stegun 7.1.26, |err| <= 1.5e-7
__device__ __forceinline__ float erf_f(float x) {
    float ax = fabsf(x);
    float t = 1.f / (1.f + 0.3275911f * ax);
    float p = t * (0.254829592f + t * (-0.284496736f + t * (1.421413741f +
              t * (-1.453152027f + t * 1.061405429f))));
    float e = 1.f - p * expf(-ax * ax);
    return copysignf(e, x);
}

// ---------------------------------------------------------------------------
// Fused multi-array fp32 -> bf16 cast (coalesced). grid = (njobs, 64)
struct CastJob { const float* src; unsigned short* dst; int n; };
struct CastArgs { CastJob j[17]; };

__global__ void cast_bf16_multi(CastArgs a) {
    CastJob jb = a.j[blockIdx.x];
    int off = (blockIdx.y * 256 + threadIdx.x) * 8;
    if (off + 8 > jb.n) return;
    float4 v0 = *reinterpret_cast<const float4*>(jb.src + off);
    float4 v1 = *reinterpret_cast<const float4*>(jb.src + off + 4);
    ushort8 u;
    u[0] = f2bs(v0.x); u[1] = f2bs(v0.y); u[2] = f2bs(v0.z); u[3] = f2bs(v0.w);
    u[4] = f2bs(v1.x); u[5] = f2bs(v1.y); u[6] = f2bs(v1.z); u[7] = f2bs(v1.w);
    *reinterpret_cast<ushort8*>(jb.dst + off) = u;
}

// Row softmax in place over [rows][1024] bf16, one WAVE per row (no barriers).
__global__ void softmax_rows(unsigned short* __restrict__ w) {
    int row = blockIdx.x * 4 + (threadIdx.x >> 6);
    int lane = threadIdx.x & 63;
    ushort4* rp = reinterpret_cast<ushort4*>(w + (size_t)row * 1024);
    float v[16];
    #pragma unroll
    for (int i = 0; i < 4; ++i) {
        ushort4 u = rp[lane + i * 64];
        v[i*4+0] = bs2f(u.x); v[i*4+1] = bs2f(u.y);
        v[i*4+2] = bs2f(u.z); v[i*4+3] = bs2f(u.w);
    }
    float m = v[0];
    #pragma unroll
    for (int i = 1; i < 16; ++i) m = fmaxf(m, v[i]);
    #pragma unroll
    for (int o = 32; o > 0; o >>= 1) m = fmaxf(m, __shfl_xor(m, o));
    float s = 0.f;
    #pragma unroll
    for (int i = 0; i < 16; ++i) { v[i] = expf(v[i] - m); s += v[i]; }
    #pragma unroll
    for (int o = 32; o > 0; o >>= 1) s += __shfl_xor(s, o);
    float inv = 1.f / s;
    #pragma unroll
    for (int i = 0; i < 4; ++i) {
        ushort4 u;
        u.x = f2bs(v[i*4+0] * inv); u.y = f2bs(v[i*4+1] * inv);
        u.z = f2bs(v[i*4+2] * inv); u.w = f2bs(v[i*4+3] * inv);
        rp[lane + i * 64] = u;
    }
}

// 5x fused 256x256 fp32->bf16 transpose. grid = (256,5)
__global__ void prep_T5(const float* s0, const float* s1, const float* s2,
                        const float* s3, const float* s4,
                        unsigned short* d0, unsigned short* d1, unsigned short* d2,
                        unsigned short* d3, unsigned short* d4) {
    int y = blockIdx.y;
    const float* W = y == 0 ? s0 : y == 1 ? s1 : y == 2 ? s2 : y == 3 ? s3 : s4;
    unsigned short* WT = y == 0 ? d0 : y == 1 ? d1 : y == 2 ? d2 : y == 3 ? d3 : d4;
    int n = blockIdx.x, k = threadIdx.x;
    WT[(size_t)n * 256 + k] = f2bs(W[(size_t)k * 256 + n]);
}

// ---------------------------------------------------------------------------
// RMS norm: one WAVE per row (V=1024), 4 rows/block, no barriers. grid = MR/4.
__global__ void rmsnorm_k(const float* __restrict__ x, unsigned short* __restrict__ xn) {
    int row = blockIdx.x * 4 + (threadIdx.x >> 6);
    int lane = threadIdx.x & 63;
    const float4* src = reinterpret_cast<const float4*>(x + (size_t)row * VV);
    float4 v[4];
    float s = 0.f;
    #pragma unroll
    for (int i = 0; i < 4; ++i) {
        v[i] = src[lane + i * 64];
        s += v[i].x*v[i].x + v[i].y*v[i].y + v[i].z*v[i].z + v[i].w*v[i].w;
    }
    #pragma unroll
    for (int o = 32; o > 0; o >>= 1) s += __shfl_xor(s, o);
    float r = rsqrtf(s * (1.f / VV) + 1.1920929e-7f);
    ushort4* dst = reinterpret_cast<ushort4*>(xn + (size_t)row * VV);
    #pragma unroll
    for (int i = 0; i < 4; ++i) {
        ushort4 u;
        u.x = f2bs(v[i].x * r); u.y = f2bs(v[i].y * r);
        u.z = f2bs(v[i].z * r); u.w = f2bs(v[i].w * r);
        dst[lane + i * 64] = u;
    }
}

// ---------------------------------------------------------------------------
// 4-in-1 bf16 transpose of qkv slices: V^T (plain) and K^T (decay-scaled).
// grid (64, 8, 16): z -> (which = z>>2, b = z&3)
__global__ void transpose4_k(const unsigned short* __restrict__ qkv,
                             unsigned short* __restrict__ vt_s,
                             unsigned short* __restrict__ vt_f,
                             unsigned short* __restrict__ kts_s,
                             unsigned short* __restrict__ kts_f,
                             const float* __restrict__ dls,
                             const float* __restrict__ dlf) {
    __shared__ unsigned short tile[32][33];
    int z = blockIdx.z, b = z & 3, which = z >> 2;
    int srcoff = which == 0 ? 512 : which == 1 ? 1280 : which == 2 ? 256 : 1024;
    unsigned short* dst = which == 0 ? vt_s : which == 1 ? vt_f : which == 2 ? kts_s : kts_f;
    float l2d = 0.f;
    if (which == 2) l2d = log2f(sigm(dls[0]));
    if (which == 3) l2d = log2f(sigm(dlf[0]));
    int t0 = blockIdx.x * 32, c0 = blockIdx.y * 32;
    int tx = threadIdx.x & 31, ty = threadIdx.x >> 5;
    const unsigned short* src = qkv + srcoff;
    #pragma unroll
    for (int i = 0; i < 4; ++i) {
        int r = ty + i * 8;
        tile[r][tx] = src[(size_t)(b * TT + t0 + r) * 1536 + c0 + tx];
    }
    __syncthreads();
    float w = (which >= 2) ? exp2f(l2d * (float)((t0 + tx) & 127)) : 1.f;
    #pragma unroll
    for (int i = 0; i < 4; ++i) {
        int r = ty + i * 8;
        dst[((size_t)b * CC + c0 + r) * TT + t0 + tx] = f2bs(bs2f(tile[tx][r]) * w);
    }
}

// ---------------------------------------------------------------------------
// Shared 64x64 GEMM core
__device__ __forceinline__ void gemm64_core(
    const unsigned short* A, int lda, const unsigned short* Bt, int ldb,
    int K, int m0, int n0, short8* As, short8* Bs, f32x4 (&acc)[2][2]) {
    const int tid = threadIdx.x;
    const int lane = tid & 63, wid = tid >> 6;
    const int wm = wid >> 1, wn = wid & 1;
    const int lrow = tid >> 2, lch = tid & 3;
    const int sws = lch ^ ((lrow >> 1) & 3);
    const unsigned short* ag = A + (size_t)(m0 + lrow) * lda + lch * 8;
    const unsigned short* bg = Bt + (size_t)(n0 + lrow) * ldb + lch * 8;
    #pragma unroll
    for (int i = 0; i < 2; ++i)
        #pragma unroll
        for (int j = 0; j < 2; ++j) acc[i][j] = {0.f, 0.f, 0.f, 0.f};
    const int g = lane >> 4;
    const int ra0 = wm * 32 + (lane & 15);
    const int rb0 = wn * 32 + (lane & 15);
    for (int k0 = 0; k0 < K; k0 += 32) {
        As[lrow * 4 + sws] = *reinterpret_cast<const short8*>(ag + k0);
        Bs[lrow * 4 + sws] = *reinterpret_cast<const short8*>(bg + k0);
        __syncthreads();
        short8 af[2], bf[2];
        #pragma unroll
        for (int i = 0; i < 2; ++i) {
            int ra = ra0 + i * 16;
            af[i] = As[ra * 4 + (g ^ ((ra >> 1) & 3))];
            int rb = rb0 + i * 16;
            bf[i] = Bs[rb * 4 + (g ^ ((rb >> 1) & 3))];
        }
        #pragma unroll
        for (int i = 0; i < 2; ++i)
            #pragma unroll
            for (int j = 0; j < 2; ++j)
                acc[i][j] = __builtin_amdgcn_mfma_f32_16x16x32_bf16(af[i], bf[j], acc[i][j], 0, 0, 0);
        __syncthreads();
    }
}

#define EPI_LOOP(MV, NV, VV_, BODY)                                            \
    {   const int lane_ = threadIdx.x & 63, wid_ = threadIdx.x >> 6;           \
        const int wm_ = wid_ >> 1, wn_ = wid_ & 1;                             \
        _Pragma("unroll")                                                      \
        for (int i_ = 0; i_ < 2; ++i_)                                         \
        { _Pragma("unroll")                                                    \
          for (int j_ = 0; j_ < 2; ++j_)                                       \
          { _Pragma("unroll")                                                  \
            for (int r_ = 0; r_ < 4; ++r_)                                     \
            { int MV = m0 + wm_ * 32 + i_ * 16 + (lane_ >> 4) * 4 + r_;        \
              int NV = n0 + wn_ * 32 + j_ * 16 + (lane_ & 15);                 \
              float VV_ = acc[i_][j_][r_];                                     \
              BODY } } } }

// ---------------------------------------------------------------------------
// Multi-job 64^2 GEMM (10 jobs, 1 launch). scale = s1*s2 (or 1 if s1==null).
struct MJob {
    const unsigned short* A; const unsigned short* Bt; unsigned short* outb;
    const float* s1; const float* s2;
    int lda, ldb, K, ldo, gx, nblk;
};
struct MJobs10 { MJob j[10]; };

__global__ __launch_bounds__(256)
void gemm_multi_k(MJobs10 js) {
    int bid = blockIdx.x, ji = 0, base = 0;
    while (bid >= base + js.j[ji].nblk) { base += js.j[ji].nblk; ++ji; }
    MJob jb = js.j[ji];
    int rem = bid - base;
    int m0 = (rem / jb.gx) * 64, n0 = (rem % jb.gx) * 64;
    __shared__ short8 As[256], Bs[256];
    f32x4 acc[2][2];
    gemm64_core(jb.A, jb.lda, jb.Bt, jb.ldb, jb.K, m0, n0, As, Bs, acc);
    float sc = jb.s1 ? jb.s1[0] * jb.s2[0] : 1.f;
    EPI_LOOP(m, n, v, { jb.outb[(size_t)m * jb.ldo + n] = f2bs(v * sc); })
}

// sigmoid(acc+bias)*aux epilogue GEMM (K=256, ldb=256). grid (4,128)
__global__ __launch_bounds__(256)
void sig_k(const unsigned short* A, int lda, const unsigned short* Bt,
           const float* bias, const unsigned short* aux, int ldaux,
           unsigned short* outb, int ldo, int coloff) {
    int m0 = blockIdx.y * 64, n0 = blockIdx.x * 64;
    __shared__ short8 As[256], Bs[256];
    f32x4 acc[2][2];
    gemm64_core(A, lda, Bt, 256, 256, m0, n0, As, Bs, acc);
    EPI_LOOP(m, n, v, {
        float s = sigm(v + bias[n]);
        float a = bs2f(aux[(size_t)m * ldaux + n]);
        outb[(size_t)m * ldo + coloff + n] = f2bs(s * a);
    })
}

// 3x gelu(z@mix+bias) batched over z. grid (4,128,3)
__global__ __launch_bounds__(256)
void gelu3_k(const unsigned short* zbuf, const unsigned short* WT_mix,
             const float* lb, const float* mb, const float* hb,
             unsigned short* hcat, unsigned short* hhigh) {
    int zi = blockIdx.z;
    const unsigned short* A = zbuf + zi * 256;
    const unsigned short* Bt = WT_mix + (size_t)zi * 65536;
    const float* bias = zi == 0 ? lb : zi == 1 ? mb : hb;
    unsigned short* outb = zi == 2 ? hhigh : hcat;
    int ldo = zi == 2 ? 256 : 768;
    int coloff = zi == 1 ? 256 : 0;
    int m0 = blockIdx.y * 64, n0 = blockIdx.x * 64;
    __shared__ short8 As[256], Bs[256];
    f32x4 acc[2][2];
    gemm64_core(A, 768, Bt, 256, 256, m0, n0, As, Bs, acc);
    EPI_LOOP(m, n, v, {
        float z = v + bias[n];
        float h = 0.5f * z * (1.f + erf_f(z * 0.70710678118654752f));
        outb[(size_t)m * ldo + coloff + n] = f2bs(h);
    })
}

// ---------------------------------------------------------------------------
// 128x128 GEMM, BK=64, single-buffer global_load_lds, XCD swizzle (ngw%8==0).
// EPI: 0 bf16 store | 3 fp32 out=addf+acc | 5 f32 store (gstate)
// BATCH: 0 plain | 1 gstate (z = sel*64+b*16+chunk)
struct EpiP {
    float* outf; const float* addf;
    unsigned short* outb; int ldo;
    const unsigned short* A2; const unsigned short* B2;
    float* outf2;
};

template<int EPI, int BATCH>
__global__ __launch_bounds__(256)
void gemm128_k(const unsigned short* __restrict__ A, int lda,
               const unsigned short* __restrict__ Bt, int ldb, int K, EpiP ep) {
    __shared__ short8 As[1024], Bs[1024];          // 128 rows x 8 chunks (64 cols)
    const int tid = threadIdx.x;
    const int lane = tid & 63, wid = tid >> 6;
    const int wm = wid >> 1, wn = wid & 1;

    int sel = 0, z2v = 0;
    if constexpr (BATCH == 1) {
        int zz = blockIdx.z; sel = zz >> 6; z2v = zz & 63;
        int zb = z2v >> 4, zp = z2v & 15;
        if (sel) { A = ep.A2; Bt = ep.B2; }
        A  += (size_t)(zb * CC) * lda + zp * 128;
        Bt += (size_t)(zb * CC) * ldb + zp * 128;
    }

    int lin = blockIdx.y * gridDim.x + blockIdx.x;
    int ngw = gridDim.x * gridDim.y;
    int sw = lin;
    if (!(ngw & 7)) sw = (lin & 7) * (ngw >> 3) + (lin >> 3);
    const int m0 = (sw / gridDim.x) * 128, n0 = (sw % gridDim.x) * 128;

    const int srow = lane >> 3, schk = (lane & 7) ^ srow;
    const unsigned short* ga = A + (size_t)(m0 + wid * 32 + srow) * lda + schk * 8;
    const unsigned short* gb = Bt + (size_t)(n0 + wid * 32 + srow) * ldb + schk * 8;
    short8* lA = &As[(wid * 32) * 8];
    short8* lB = &Bs[(wid * 32) * 8];

    const int fr = lane & 15, fg = lane >> 4;

    f32x4 acc[4][4];
    #pragma unroll
    for (int i = 0; i < 4; ++i)
        #pragma unroll
        for (int j = 0; j < 4; ++j) acc[i][j] = {0.f, 0.f, 0.f, 0.f};

    for (int k0 = 0; k0 < K; k0 += 64) {
        #pragma unroll
        for (int q = 0; q < 4; ++q) {
            gl_lds16(ga + (size_t)(q * 8) * lda + k0, lA + q * 64);
            gl_lds16(gb + (size_t)(q * 8) * ldb + k0, lB + q * 64);
        }
        __syncthreads();
        #pragma unroll
        for (int kk = 0; kk < 2; ++kk) {
            short8 af[4], bf[4];
            #pragma unroll
            for (int i = 0; i < 4; ++i) {
                int ra = wm * 64 + i * 16 + fr;
                af[i] = As[ra * 8 + ((kk * 4 + fg) ^ (ra & 7))];
                int rb = wn * 64 + i * 16 + fr;
                bf[i] = Bs[rb * 8 + ((kk * 4 + fg) ^ (rb & 7))];
            }
            #pragma unroll
            for (int i = 0; i < 4; ++i)
                #pragma unroll
                for (int j = 0; j < 4; ++j)
                    acc[i][j] = __builtin_amdgcn_mfma_f32_16x16x32_bf16(af[i], bf[j], acc[i][j], 0, 0, 0);
        }
        __syncthreads();
    }

    float* gout = nullptr;
    if constexpr (EPI == 5) gout = (sel ? ep.outf2 : ep.outf) + (size_t)z2v * 65536;

    #pragma unroll
    for (int i = 0; i < 4; ++i) {
        #pragma unroll
        for (int j = 0; j < 4; ++j) {
            #pragma unroll
            for (int r = 0; r < 4; ++r) {
                int m = m0 + wm * 64 + i * 16 + fg * 4 + r;
                int n = n0 + wn * 64 + j * 16 + fr;
                float v = acc[i][j][r];
                if constexpr (EPI == 0) {
                    ep.outb[(size_t)m * ep.ldo + n] = f2bs(v);
                } else if constexpr (EPI == 3) {
                    size_t idx = (size_t)m * ep.ldo + n;
                    ep.outf[idx] = ep.addf[idx] + v;
                } else {
                    gout[(size_t)m * 256 + n] = v;
                }
            }
        }
    }
}

// ---------------------------------------------------------------------------
// Retrieval: intra-chunk decay attention + FUSED inter-chunk state term.
// Inter: racc starts with Q @ Ssuf[chunk] (k-range split across the 4 waves),
// scaled per-row by d^(127 - t%128), then the intra s-loop accumulates on top.
// Cross-wave reduction sums both parts. Saves the separate inter kernel, the
// Q re-read, and the bf16 RMW on rcat/rfast.
__global__ __launch_bounds__(256)
void attn_k(const unsigned short* __restrict__ qkv,
            const unsigned short* __restrict__ vt_s,
            const unsigned short* __restrict__ vt_f,
            const unsigned short* __restrict__ ST_s,
            const unsigned short* __restrict__ ST_f,
            const float* __restrict__ dls, const float* __restrict__ dlf,
            unsigned short* __restrict__ rcat, unsigned short* __restrict__ rfast) {
    int y = blockIdx.y;
    int qoff = y ? 768 : 0, koff = y ? 1024 : 256;
    const unsigned short* vt = y ? vt_f : vt_s;
    unsigned short* rout = y ? rfast : rcat;
    int ldr = y ? 256 : 512;
    float l2d = log2f(sigm(y ? dlf[0] : dls[0]));

    int blk = blockIdx.x;
    int b = blk >> 7;
    int t0 = (blk & 127) << 4;
    int tid = threadIdx.x;
    int lane = tid & 63, wid = tid >> 6;

    __shared__ short8 Pl[4][64];
    __shared__ float  red[16][260];

    short8 qf[8];
    const size_t rowq = (size_t)(b * TT + t0 + (lane & 15)) * 1536 + qoff + (lane >> 4) * 8;
    #pragma unroll
    for (int ch = 0; ch < 8; ++ch)
        qf[ch] = *reinterpret_cast<const short8*>(qkv + rowq + ch * 32);

    f32x4 racc[16];
    #pragma unroll
    for (int i = 0; i < 16; ++i) racc[i] = {0.f, 0.f, 0.f, 0.f};

    const int tl = (lane >> 4) * 4;

    // ---- inter-chunk term (rows attend to later chunks) ----
    int p = (t0 >> 7) & 15;         // chunk index within batch
    if (p < 15) {
        const unsigned short* stb = (y ? ST_f : ST_s)
            + (((size_t)(b * 15 + p)) << 16)
            + (size_t)(lane & 15) * 256 + (lane >> 4) * 8;
        #pragma unroll
        for (int kc2 = 0; kc2 < 2; ++kc2) {
            int kc = wid * 2 + kc2;
            #pragma unroll
            for (int nt = 0; nt < 16; ++nt) {
                short8 stf = *reinterpret_cast<const short8*>(stb + (size_t)nt * 16 * 256 + kc * 32);
                racc[nt] = __builtin_amdgcn_mfma_f32_16x16x32_bf16(qf[kc], stf, racc[nt], 0, 0, 0);
            }
        }
        float base = (float)(127 - ((t0 & 127) + tl));
        #pragma unroll
        for (int nt = 0; nt < 16; ++nt)
            #pragma unroll
            for (int r = 0; r < 4; ++r)
                racc[nt][r] *= exp2f(l2d * (base - (float)r));
    }

    // ---- intra-chunk dense part ----
    unsigned short* pb = reinterpret_cast<unsigned short*>(&Pl[wid][0]);
    int sBeg = t0 & ~31;
    int sEnd = (t0 & ~127) + 128;

    for (int s0 = sBeg + wid * 32; s0 < sEnd; s0 += 128) {
        #pragma unroll
        for (int h = 0; h < 2; ++h) {
            f32x4 sacc = {0.f, 0.f, 0.f, 0.f};
            const unsigned short* kb =
                qkv + (size_t)(b * TT + s0 + h * 16 + (lane & 15)) * 1536 + koff + (lane >> 4) * 8;
            #pragma unroll
            for (int ch = 0; ch < 8; ++ch) {
                short8 kf = *reinterpret_cast<const short8*>(kb + ch * 32);
                sacc = __builtin_amdgcn_mfma_f32_16x16x32_bf16(qf[ch], kf, sacc, 0, 0, 0);
            }
            int scol = s0 + h * 16 + (lane & 15);
            #pragma unroll
            for (int r = 0; r < 4; ++r) {
                int trow = t0 + tl + r;
                int d = scol - trow;
                float w = (d > 0) ? exp2f(l2d * (float)(d - 1)) : 0.f;
                int prow = tl + r, pcol = h * 16 + (lane & 15);
                int swp = (pcol >> 3) ^ ((prow >> 1) & 3);
                pb[(prow * 4 + swp) * 8 + (pcol & 7)] = f2bs(sacc[r] * w);
            }
        }
        asm volatile("s_waitcnt lgkmcnt(0)" ::: "memory");
        __builtin_amdgcn_sched_barrier(0);
        short8 pf;
        { int prow = lane & 15; pf = Pl[wid][prow * 4 + ((lane >> 4) ^ ((prow >> 1) & 3))]; }
        const unsigned short* vb = vt + ((size_t)b * CC + (lane & 15)) * TT + s0 + (lane >> 4) * 8;
        #pragma unroll
        for (int nt = 0; nt < 16; ++nt) {
            short8 vf = *reinterpret_cast<const short8*>(vb + (size_t)nt * 16 * TT);
            racc[nt] = __builtin_amdgcn_mfma_f32_16x16x32_bf16(pf, vf, racc[nt], 0, 0, 0);
        }
    }

    for (int w = 0; w < 4; ++w) {
        if (wid == w) {
            #pragma unroll
            for (int nt = 0; nt < 16; ++nt)
                #pragma unroll
                for (int r = 0; r < 4; ++r) {
                    int row = tl + r, col = nt * 16 + (lane & 15);
                    if (w == 0) red[row][col] = racc[nt][r];
                    else        red[row][col] += racc[nt][r];
                }
        }
        __syncthreads();
    }

    {
        int row = tid >> 4, c0 = (tid & 15) * 16;
        ushort8 lo, hi;
        #pragma unroll
        for (int j = 0; j < 8; ++j) lo[j] = f2bs(red[row][c0 + j]);
        #pragma unroll
        for (int j = 0; j < 8; ++j) hi[j] = f2bs(red[row][c0 + 8 + j]);
        unsigned short* dst = rout + (size_t)(b * TT + t0 + row) * ldr + c0;
        *reinterpret_cast<ushort8*>(dst)     = lo;
        *reinterpret_cast<ushort8*>(dst + 8) = hi;
    }
}

// ---------------------------------------------------------------------------
// Elementwise suffix scan over transposed chunk states (G' = G^T layout).
__global__ void scan_states2(const float* __restrict__ Gs, const float* __restrict__ Gf,
                             const float* __restrict__ dls, const float* __restrict__ dlf,
                             unsigned short* __restrict__ STs, unsigned short* __restrict__ STf) {
    int sel = blockIdx.z;
    const float* G = sel ? Gf : Gs;
    unsigned short* ST = sel ? STf : STs;
    float d = sigm(sel ? dlf[0] : dls[0]);
    int b = blockIdx.y;
    int e0 = (blockIdx.x * 256 + threadIdx.x) * 4;
    float dL = exp2f(log2f(d) * 128.f);
    float4 s = {0.f, 0.f, 0.f, 0.f};
    for (int c = 15; c >= 1; --c) {
        float4 g = *reinterpret_cast<const float4*>(G + (((size_t)(b * 16 + c)) << 16) + e0);
        s.x = g.x + dL * s.x; s.y = g.y + dL * s.y;
        s.z = g.z + dL * s.z; s.w = g.w + dL * s.w;
        ushort4 o;
        o.x = f2bs(s.x); o.y = f2bs(s.y); o.z = f2bs(s.z); o.w = f2bs(s.w);
        *reinterpret_cast<ushort4*>(ST + (((size_t)(b * 15 + c - 1)) << 16) + e0) = o;
    }
}

// ---------------------------------------------------------------------------
extern "C" void kernel_launch(void* const* d_in, const int* in_sizes, int n_in,
                              void* d_out, int out_size, void* d_ws, size_t ws_size,
                              hipStream_t stream) {
    (void)in_sizes; (void)n_in; (void)out_size; (void)ws_size;
    const float* x          = (const float*)d_in[0];
    const float* basis_low  = (const float*)d_in[1];
    const float* basis_mid  = (const float*)d_in[2];
    const float* basis_high = (const float*)d_in[3];
    const float* slow_q = (const float*)d_in[4];
    const float* slow_k = (const float*)d_in[5];
    const float* slow_v = (const float*)d_in[6];
    const float* slow_o = (const float*)d_in[7];
    const float* slow_decay = (const float*)d_in[8];
    const float* slow_scale = (const float*)d_in[9];
    const float* fast_q = (const float*)d_in[10];
    const float* fast_k = (const float*)d_in[11];
    const float* fast_v = (const float*)d_in[12];
    const float* fast_o = (const float*)d_in[13];
    const float* fast_decay = (const float*)d_in[14];
    const float* fast_scale = (const float*)d_in[15];
    const float* low_read  = (const float*)d_in[16];
    const float* low_write = (const float*)d_in[17];
    const float* low_mix   = (const float*)d_in[18];
    const float* low_bias  = (const float*)d_in[19];
    const float* low_oscale= (const float*)d_in[20];
    const float* mid_read  = (const float*)d_in[21];
    const float* mid_write = (const float*)d_in[22];
    const float* mid_mix   = (const float*)d_in[23];
    const float* mid_bias  = (const float*)d_in[24];
    const float* mid_oscale= (const float*)d_in[25];
    const float* high_read  = (const float*)d_in[26];
    const float* high_write = (const float*)d_in[27];
    const float* high_mix   = (const float*)d_in[28];
    const float* high_bias  = (const float*)d_in[29];
    const float* high_oscale= (const float*)d_in[30];
    const float* tg_w    = (const float*)d_in[31];
    const float* tg_b    = (const float*)d_in[32];
    const float* alpha_w = (const float*)d_in[33];
    const float* alpha_b = (const float*)d_in[34];
    const float* mem_slow_scale = (const float*)d_in[35];
    const float* mem_fast_scale = (const float*)d_in[36];
    const float* op_low_scale   = (const float*)d_in[37];
    const float* op_mid_scale   = (const float*)d_in[38];
    const float* op_high_scale  = (const float*)d_in[39];
    float* out = (float*)d_out;

    char* ws = (char*)d_ws;
    size_t off = 0;
    auto alloc = [&](size_t n) { char* p = ws + off; off += (n + 255) & ~(size_t)255; return p; };
    unsigned short* WT_p1   = (unsigned short*)alloc((size_t)6 * CC * VV * 2);   // [1536][1024]
    unsigned short* WT_read = (unsigned short*)alloc((size_t)3 * CC * VV * 2);   // [768][1024]
    unsigned short* Wcat_o  = (unsigned short*)alloc((size_t)VV * 512 * 2);
    unsigned short* Wcat_w  = (unsigned short*)alloc((size_t)VV * 768 * 2);
    unsigned short* WT_mix  = (unsigned short*)alloc((size_t)3 * 65536 * 2);
    unsigned short* WT_tg   = (unsigned short*)alloc((size_t)65536 * 2);
    unsigned short* WT_al   = (unsigned short*)alloc((size_t)65536 * 2);
    unsigned short* bb_low  = (unsigned short*)alloc((size_t)VV * 32 * 2);
    unsigned short* bb_mid  = (unsigned short*)alloc((size_t)VV * 64 * 2);
    unsigned short* bb_high = (unsigned short*)alloc((size_t)VV * 128 * 2);
    unsigned short* cqkv_l  = (unsigned short*)alloc((size_t)768 * 32 * 2);
    unsigned short* cqkv_h  = (unsigned short*)alloc((size_t)768 * 128 * 2);
    unsigned short* crd_l   = (unsigned short*)alloc((size_t)256 * 32 * 2);
    unsigned short* crd_m   = (unsigned short*)alloc((size_t)256 * 64 * 2);
    unsigned short* crd_h   = (unsigned short*)alloc((size_t)256 * 128 * 2);
    unsigned short* cO_s    = (unsigned short*)alloc((size_t)256 * 32 * 2);
    unsigned short* cO_f    = (unsigned short*)alloc((size_t)256 * 128 * 2);
    unsigned short* cW_l    = (unsigned short*)alloc((size_t)256 * 32 * 2);
    unsigned short* cW_m    = (unsigned short*)alloc((size_t)256 * 64 * 2);
    unsigned short* cW_h    = (unsigned short*)alloc((size_t)256 * 128 * 2);
    unsigned short* xn      = (unsigned short*)alloc((size_t)MR * VV * 2);       // reused: Gs, ph2 xn
    unsigned short* qkv     = (unsigned short*)alloc((size_t)MR * 1536 * 2);
    unsigned short* vt_s    = (unsigned short*)alloc((size_t)BB * CC * TT * 2);
    unsigned short* vt_f    = (unsigned short*)alloc((size_t)BB * CC * TT * 2);
    unsigned short* kts_s   = (unsigned short*)alloc((size_t)BB * CC * TT * 2);
    unsigned short* kts_f   = (unsigned short*)alloc((size_t)BB * CC * TT * 2);
    unsigned short* ST_s    = (unsigned short*)alloc((size_t)BB * 15 * 65536 * 2);
    unsigned short* ST_f    = (unsigned short*)alloc((size_t)BB * 15 * 65536 * 2);
    unsigned short* rcat    = (unsigned short*)alloc((size_t)MR * 512 * 2);
    unsigned short* rfast   = (unsigned short*)alloc((size_t)MR * CC * 2);
    unsigned short* hhigh   = (unsigned short*)alloc((size_t)MR * CC * 2);
    // overlays
    float* Gs = (float*)xn;                              // 64 states fp32 = 16.7MB
    float* Gf = (float*)rcat;                            // 64 states fp32 (rcat written later)
    unsigned short* z    = qkv;
    unsigned short* hcat = qkv + (size_t)MR * 768;

    // ---- weight prep: casts ----
    {
        CastArgs ca;
        int i = 0;
        auto J = [&](const float* s, unsigned short* d, int n) { ca.j[i].src = s; ca.j[i].dst = d; ca.j[i].n = n; ++i; };
        J(basis_low,  bb_low,  VV * 32);
        J(basis_mid,  bb_mid,  VV * 64);
        J(basis_high, bb_high, VV * 128);
        J(slow_q, cqkv_l + 0 * 256 * 32, 256 * 32);
        J(slow_k, cqkv_l + 1 * 256 * 32, 256 * 32);
        J(slow_v, cqkv_l + 2 * 256 * 32, 256 * 32);
        J(fast_q, cqkv_h + 0 * 256 * 128, 256 * 128);
        J(fast_k, cqkv_h + 1 * 256 * 128, 256 * 128);
        J(fast_v, cqkv_h + 2 * 256 * 128, 256 * 128);
        J(low_read,  crd_l, 256 * 32);
        J(mid_read,  crd_m, 256 * 64);
        J(high_read, crd_h, 256 * 128);
        J(slow_o,    cO_s,  256 * 32);
        J(fast_o,    cO_f,  256 * 128);
        J(low_write, cW_l,  256 * 32);
        J(mid_write, cW_m,  256 * 64);
        J(high_write,cW_h,  256 * 128);
        cast_bf16_multi<<<dim3(17, 64), 256, 0, stream>>>(ca);
    }

    // ---- all 10 prep GEMMs in ONE launch (logits + projection weights) ----
    {
        MJobs10 js;
        auto S = [&](int i, const unsigned short* A, int lda, const unsigned short* B, int K,
                     unsigned short* o, int ldo, int gx, int nb,
                     const float* s1, const float* s2) {
            js.j[i].A = A; js.j[i].Bt = B; js.j[i].outb = o; js.j[i].s1 = s1; js.j[i].s2 = s2;
            js.j[i].lda = lda; js.j[i].ldb = K; js.j[i].K = K; js.j[i].ldo = ldo; js.j[i].gx = gx; js.j[i].nblk = nb;
        };
        S(0, cqkv_l, 32,  bb_low,  32,  WT_p1,                     VV, 16, 192, nullptr, nullptr);
        S(1, cqkv_h, 128, bb_high, 128, WT_p1 + (size_t)768 * VV,  VV, 16, 192, nullptr, nullptr);
        S(2, crd_l,  32,  bb_low,  32,  WT_read,                    VV, 16, 64, nullptr, nullptr);
        S(3, crd_m,  64,  bb_mid,  64,  WT_read + (size_t)256 * VV, VV, 16, 64, nullptr, nullptr);
        S(4, crd_h,  128, bb_high, 128, WT_read + (size_t)512 * VV, VV, 16, 64, nullptr, nullptr);
        S(5, bb_low,  32,  cO_s, 32,  Wcat_o,       512, 4, 64, slow_scale,  mem_slow_scale);
        S(6, bb_high, 128, cO_f, 128, Wcat_o + 256, 512, 4, 64, fast_scale,  mem_fast_scale);
        S(7, bb_low,  32,  cW_l, 32,  Wcat_w,       768, 4, 64, low_oscale,  op_low_scale);
        S(8, bb_mid,  64,  cW_m, 64,  Wcat_w + 256, 768, 4, 64, mid_oscale,  op_mid_scale);
        S(9, bb_high, 128, cW_h, 128, Wcat_w + 512, 768, 4, 64, high_oscale, op_high_scale);
        gemm_multi_k<<<896, 256, 0, stream>>>(js);
    }
    softmax_rows<<<576, 256, 0, stream>>>(WT_p1);    // 2304 rows, 4 rows/block

    prep_T5<<<dim3(256, 5), 256, 0, stream>>>(tg_w, alpha_w, low_mix, mid_mix, high_mix,
                                              WT_tg, WT_al, WT_mix, WT_mix + 65536, WT_mix + 131072);

    // ---- phase 1 ----
    rmsnorm_k<<<MR / 4, 256, 0, stream>>>(x, xn);
    { EpiP ep{}; ep.outb = qkv; ep.ldo = 1536;
      gemm128_k<0,0><<<dim3(12, 64), 256, 0, stream>>>(xn, 1024, WT_p1, 1024, 1024, ep); }
    transpose4_k<<<dim3(64, 8, 16), 256, 0, stream>>>(qkv, vt_s, vt_f, kts_s, kts_f, slow_decay, fast_decay);
    { EpiP ep{}; ep.outf = Gs; ep.outf2 = Gf; ep.A2 = vt_f; ep.B2 = kts_f;
      gemm128_k<5,1><<<dim3(2, 2, 128), 256, 0, stream>>>(vt_s, TT, kts_s, TT, 128, ep); }
    scan_states2<<<dim3(64, 4, 2), 256, 0, stream>>>(Gs, Gf, slow_decay, fast_decay, ST_s, ST_f);
    attn_k<<<dim3(512, 2), 256, 0, stream>>>(qkv, vt_s, vt_f, ST_s, ST_f,
                                             slow_decay, fast_decay, rcat, rfast);
    sig_k<<<dim3(4, 128), 256, 0, stream>>>(rcat, 512, WT_tg, tg_b, rfast, 256, rcat, 512, 256);
    { EpiP ep{}; ep.outf = out; ep.addf = x; ep.ldo = 1024;
      gemm128_k<3,0><<<dim3(8, 64), 256, 0, stream>>>(rcat, 512, Wcat_o, 512, 512, ep); }

    // ---- phase 2 ----
    rmsnorm_k<<<MR / 4, 256, 0, stream>>>(out, xn);
    { EpiP ep{}; ep.outb = z; ep.ldo = 768;
      gemm128_k<0,0><<<dim3(6, 64), 256, 0, stream>>>(xn, 1024, WT_read, 1024, 1024, ep); }
    gelu3_k<<<dim3(4, 128, 3), 256, 0, stream>>>(z, WT_mix, low_bias, mid_bias, high_bias, hcat, hhigh);
    sig_k<<<dim3(4, 128), 256, 0, stream>>>(hcat, 768, WT_al, alpha_b, hhigh, 256, hcat, 768, 512);
    { EpiP ep{}; ep.outf = out; ep.addf = out; ep.ldo = 1024;
      gemm128_k<3,0><<<dim3(6, 64), 256, 0, stream>>>(hcat, 768, Wcat_w, 768, 768, ep); }
}

// Round 15
// 285.113 us; speedup vs baseline: 1.0226x; 1.0226x over previous
//
#include <hip/hip_runtime.h>
#include <math.h>

#define BB 4
#define TT 2048
#define VV 1024
#define CC 256
#define MR (BB*TT)   // 8192 rows

using short8  = __attribute__((ext_vector_type(8))) short;
using ushort8 = __attribute__((ext_vector_type(8))) unsigned short;
using f32x4   = __attribute__((ext_vector_type(4))) float;

__device__ __forceinline__ float bs2f(unsigned short s) {
    return __uint_as_float(((unsigned int)s) << 16);
}
__device__ __forceinline__ unsigned short f2bs(float f) {
    unsigned int u = __float_as_uint(f);
    u += 0x7fffu + ((u >> 16) & 1u);          // round-to-nearest-even
    return (unsigned short)(u >> 16);
}
__device__ __forceinline__ void gl_lds16(const void* g, void* l) {
    __builtin_amdgcn_global_load_lds(
        (const __attribute__((address_space(1))) unsigned int*)g,
        (__attribute__((address_space(3))) unsigned int*)l, 16, 0, 0);
}
__device__ __forceinline__ float sigm(float x) { return 1.f / (1.f + expf(-x)); }
// Abramowitz-Stegun 7.1.26, |err| <= 1.5e-7
__device__ __forceinline__ float erf_f(float x) {
    float ax = fabsf(x);
    float t = 1.f / (1.f + 0.3275911f * ax);
    float p = t * (0.254829592f + t * (-0.284496736f + t * (1.421413741f +
              t * (-1.453152027f + t * 1.061405429f))));
    float e = 1.f - p * expf(-ax * ax);
    return copysignf(e, x);
}

// ---------------------------------------------------------------------------
// Fused multi-array fp32 -> bf16 cast (coalesced). grid = (njobs, 64)
struct CastJob { const float* src; unsigned short* dst; int n; };
struct CastArgs { CastJob j[17]; };

__global__ void cast_bf16_multi(CastArgs a) {
    CastJob jb = a.j[blockIdx.x];
    int off = (blockIdx.y * 256 + threadIdx.x) * 8;
    if (off + 8 > jb.n) return;
    float4 v0 = *reinterpret_cast<const float4*>(jb.src + off);
    float4 v1 = *reinterpret_cast<const float4*>(jb.src + off + 4);
    ushort8 u;
    u[0] = f2bs(v0.x); u[1] = f2bs(v0.y); u[2] = f2bs(v0.z); u[3] = f2bs(v0.w);
    u[4] = f2bs(v1.x); u[5] = f2bs(v1.y); u[6] = f2bs(v1.z); u[7] = f2bs(v1.w);
    *reinterpret_cast<ushort8*>(jb.dst + off) = u;
}

// Row softmax in place over [rows][1024] bf16, one WAVE per row (no barriers).
__global__ void softmax_rows(unsigned short* __restrict__ w) {
    int row = blockIdx.x * 4 + (threadIdx.x >> 6);
    int lane = threadIdx.x & 63;
    ushort4* rp = reinterpret_cast<ushort4*>(w + (size_t)row * 1024);
    float v[16];
    #pragma unroll
    for (int i = 0; i < 4; ++i) {
        ushort4 u = rp[lane + i * 64];
        v[i*4+0] = bs2f(u.x); v[i*4+1] = bs2f(u.y);
        v[i*4+2] = bs2f(u.z); v[i*4+3] = bs2f(u.w);
    }
    float m = v[0];
    #pragma unroll
    for (int i = 1; i < 16; ++i) m = fmaxf(m, v[i]);
    #pragma unroll
    for (int o = 32; o > 0; o >>= 1) m = fmaxf(m, __shfl_xor(m, o));
    float s = 0.f;
    #pragma unroll
    for (int i = 0; i < 16; ++i) { v[i] = expf(v[i] - m); s += v[i]; }
    #pragma unroll
    for (int o = 32; o > 0; o >>= 1) s += __shfl_xor(s, o);
    float inv = 1.f / s;
    #pragma unroll
    for (int i = 0; i < 4; ++i) {
        ushort4 u;
        u.x = f2bs(v[i*4+0] * inv); u.y = f2bs(v[i*4+1] * inv);
        u.z = f2bs(v[i*4+2] * inv); u.w = f2bs(v[i*4+3] * inv);
        rp[lane + i * 64] = u;
    }
}

// 5x fused 256x256 fp32->bf16 transpose. grid = (256,5)
__global__ void prep_T5(const float* s0, const float* s1, const float* s2,
                        const float* s3, const float* s4,
                        unsigned short* d0, unsigned short* d1, unsigned short* d2,
                        unsigned short* d3, unsigned short* d4) {
    int y = blockIdx.y;
    const float* W = y == 0 ? s0 : y == 1 ? s1 : y == 2 ? s2 : y == 3 ? s3 : s4;
    unsigned short* WT = y == 0 ? d0 : y == 1 ? d1 : y == 2 ? d2 : y == 3 ? d3 : d4;
    int n = blockIdx.x, k = threadIdx.x;
    WT[(size_t)n * 256 + k] = f2bs(W[(size_t)k * 256 + n]);
}

// ---------------------------------------------------------------------------
// RMS norm: one WAVE per row (V=1024), 4 rows/block, no barriers. grid = MR/4.
__global__ void rmsnorm_k(const float* __restrict__ x, unsigned short* __restrict__ xn) {
    int row = blockIdx.x * 4 + (threadIdx.x >> 6);
    int lane = threadIdx.x & 63;
    const float4* src = reinterpret_cast<const float4*>(x + (size_t)row * VV);
    float4 v[4];
    float s = 0.f;
    #pragma unroll
    for (int i = 0; i < 4; ++i) {
        v[i] = src[lane + i * 64];
        s += v[i].x*v[i].x + v[i].y*v[i].y + v[i].z*v[i].z + v[i].w*v[i].w;
    }
    #pragma unroll
    for (int o = 32; o > 0; o >>= 1) s += __shfl_xor(s, o);
    float r = rsqrtf(s * (1.f / VV) + 1.1920929e-7f);
    ushort4* dst = reinterpret_cast<ushort4*>(xn + (size_t)row * VV);
    #pragma unroll
    for (int i = 0; i < 4; ++i) {
        ushort4 u;
        u.x = f2bs(v[i].x * r); u.y = f2bs(v[i].y * r);
        u.z = f2bs(v[i].z * r); u.w = f2bs(v[i].w * r);
        dst[lane + i * 64] = u;
    }
}

// ---------------------------------------------------------------------------
// 4-in-1 bf16 transpose of qkv slices: V^T (plain) and K^T (decay-scaled).
// grid (64, 8, 16): z -> (which = z>>2, b = z&3)
__global__ void transpose4_k(const unsigned short* __restrict__ qkv,
                             unsigned short* __restrict__ vt_s,
                             unsigned short* __restrict__ vt_f,
                             unsigned short* __restrict__ kts_s,
                             unsigned short* __restrict__ kts_f,
                             const float* __restrict__ dls,
                             const float* __restrict__ dlf) {
    __shared__ unsigned short tile[32][33];
    int z = blockIdx.z, b = z & 3, which = z >> 2;
    int srcoff = which == 0 ? 512 : which == 1 ? 1280 : which == 2 ? 256 : 1024;
    unsigned short* dst = which == 0 ? vt_s : which == 1 ? vt_f : which == 2 ? kts_s : kts_f;
    float l2d = 0.f;
    if (which == 2) l2d = log2f(sigm(dls[0]));
    if (which == 3) l2d = log2f(sigm(dlf[0]));
    int t0 = blockIdx.x * 32, c0 = blockIdx.y * 32;
    int tx = threadIdx.x & 31, ty = threadIdx.x >> 5;
    const unsigned short* src = qkv + srcoff;
    #pragma unroll
    for (int i = 0; i < 4; ++i) {
        int r = ty + i * 8;
        tile[r][tx] = src[(size_t)(b * TT + t0 + r) * 1536 + c0 + tx];
    }
    __syncthreads();
    float w = (which >= 2) ? exp2f(l2d * (float)((t0 + tx) & 127)) : 1.f;
    #pragma unroll
    for (int i = 0; i < 4; ++i) {
        int r = ty + i * 8;
        dst[((size_t)b * CC + c0 + r) * TT + t0 + tx] = f2bs(bs2f(tile[tx][r]) * w);
    }
}

// ---------------------------------------------------------------------------
// Shared 64x64 GEMM core
__device__ __forceinline__ void gemm64_core(
    const unsigned short* A, int lda, const unsigned short* Bt, int ldb,
    int K, int m0, int n0, short8* As, short8* Bs, f32x4 (&acc)[2][2]) {
    const int tid = threadIdx.x;
    const int lane = tid & 63, wid = tid >> 6;
    const int wm = wid >> 1, wn = wid & 1;
    const int lrow = tid >> 2, lch = tid & 3;
    const int sws = lch ^ ((lrow >> 1) & 3);
    const unsigned short* ag = A + (size_t)(m0 + lrow) * lda + lch * 8;
    const unsigned short* bg = Bt + (size_t)(n0 + lrow) * ldb + lch * 8;
    #pragma unroll
    for (int i = 0; i < 2; ++i)
        #pragma unroll
        for (int j = 0; j < 2; ++j) acc[i][j] = {0.f, 0.f, 0.f, 0.f};
    const int g = lane >> 4;
    const int ra0 = wm * 32 + (lane & 15);
    const int rb0 = wn * 32 + (lane & 15);
    for (int k0 = 0; k0 < K; k0 += 32) {
        As[lrow * 4 + sws] = *reinterpret_cast<const short8*>(ag + k0);
        Bs[lrow * 4 + sws] = *reinterpret_cast<const short8*>(bg + k0);
        __syncthreads();
        short8 af[2], bf[2];
        #pragma unroll
        for (int i = 0; i < 2; ++i) {
            int ra = ra0 + i * 16;
            af[i] = As[ra * 4 + (g ^ ((ra >> 1) & 3))];
            int rb = rb0 + i * 16;
            bf[i] = Bs[rb * 4 + (g ^ ((rb >> 1) & 3))];
        }
        #pragma unroll
        for (int i = 0; i < 2; ++i)
            #pragma unroll
            for (int j = 0; j < 2; ++j)
                acc[i][j] = __builtin_amdgcn_mfma_f32_16x16x32_bf16(af[i], bf[j], acc[i][j], 0, 0, 0);
        __syncthreads();
    }
}

#define EPI_LOOP(MV, NV, VV_, BODY)                                            \
    {   const int lane_ = threadIdx.x & 63, wid_ = threadIdx.x >> 6;           \
        const int wm_ = wid_ >> 1, wn_ = wid_ & 1;                             \
        _Pragma("unroll")                                                      \
        for (int i_ = 0; i_ < 2; ++i_)                                         \
        { _Pragma("unroll")                                                    \
          for (int j_ = 0; j_ < 2; ++j_)                                       \
          { _Pragma("unroll")                                                  \
            for (int r_ = 0; r_ < 4; ++r_)                                     \
            { int MV = m0 + wm_ * 32 + i_ * 16 + (lane_ >> 4) * 4 + r_;        \
              int NV = n0 + wn_ * 32 + j_ * 16 + (lane_ & 15);                 \
              float VV_ = acc[i_][j_][r_];                                     \
              BODY } } } }

// ---------------------------------------------------------------------------
// Multi-job 64^2 GEMM (10 jobs, 1 launch). scale = s1*s2 (or 1 if s1==null).
struct MJob {
    const unsigned short* A; const unsigned short* Bt; unsigned short* outb;
    const float* s1; const float* s2;
    int lda, ldb, K, ldo, gx, nblk;
};
struct MJobs10 { MJob j[10]; };

__global__ __launch_bounds__(256)
void gemm_multi_k(MJobs10 js) {
    int bid = blockIdx.x, ji = 0, base = 0;
    while (bid >= base + js.j[ji].nblk) { base += js.j[ji].nblk; ++ji; }
    MJob jb = js.j[ji];
    int rem = bid - base;
    int m0 = (rem / jb.gx) * 64, n0 = (rem % jb.gx) * 64;
    __shared__ short8 As[256], Bs[256];
    f32x4 acc[2][2];
    gemm64_core(jb.A, jb.lda, jb.Bt, jb.ldb, jb.K, m0, n0, As, Bs, acc);
    float sc = jb.s1 ? jb.s1[0] * jb.s2[0] : 1.f;
    EPI_LOOP(m, n, v, { jb.outb[(size_t)m * jb.ldo + n] = f2bs(v * sc); })
}

// sigmoid(acc+bias)*aux epilogue GEMM (K=256, ldb=256). grid (4,128)
__global__ __launch_bounds__(256)
void sig_k(const unsigned short* A, int lda, const unsigned short* Bt,
           const float* bias, const unsigned short* aux, int ldaux,
           unsigned short* outb, int ldo, int coloff) {
    int m0 = blockIdx.y * 64, n0 = blockIdx.x * 64;
    __shared__ short8 As[256], Bs[256];
    f32x4 acc[2][2];
    gemm64_core(A, lda, Bt, 256, 256, m0, n0, As, Bs, acc);
    EPI_LOOP(m, n, v, {
        float s = sigm(v + bias[n]);
        float a = bs2f(aux[(size_t)m * ldaux + n]);
        outb[(size_t)m * ldo + coloff + n] = f2bs(s * a);
    })
}

// 3x gelu(z@mix+bias) batched over z. grid (4,128,3)
__global__ __launch_bounds__(256)
void gelu3_k(const unsigned short* zbuf, const unsigned short* WT_mix,
             const float* lb, const float* mb, const float* hb,
             unsigned short* hcat, unsigned short* hhigh) {
    int zi = blockIdx.z;
    const unsigned short* A = zbuf + zi * 256;
    const unsigned short* Bt = WT_mix + (size_t)zi * 65536;
    const float* bias = zi == 0 ? lb : zi == 1 ? mb : hb;
    unsigned short* outb = zi == 2 ? hhigh : hcat;
    int ldo = zi == 2 ? 256 : 768;
    int coloff = zi == 1 ? 256 : 0;
    int m0 = blockIdx.y * 64, n0 = blockIdx.x * 64;
    __shared__ short8 As[256], Bs[256];
    f32x4 acc[2][2];
    gemm64_core(A, 768, Bt, 256, 256, m0, n0, As, Bs, acc);
    EPI_LOOP(m, n, v, {
        float z = v + bias[n];
        float h = 0.5f * z * (1.f + erf_f(z * 0.70710678118654752f));
        outb[(size_t)m * ldo + coloff + n] = f2bs(h);
    })
}

// ---------------------------------------------------------------------------
// 128x128 GEMM, BK=64, single-buffer global_load_lds, XCD swizzle (ngw%8==0).
// EPI: 0 bf16 store | 3 fp32 out=addf+acc | 5 f32 store (gstate)
// BATCH: 0 plain | 1 gstate (z = sel*64+b*16+chunk)
struct EpiP {
    float* outf; const float* addf;
    unsigned short* outb; int ldo;
    const unsigned short* A2; const unsigned short* B2;
    float* outf2;
};

template<int EPI, int BATCH>
__global__ __launch_bounds__(256)
void gemm128_k(const unsigned short* __restrict__ A, int lda,
               const unsigned short* __restrict__ Bt, int ldb, int K, EpiP ep) {
    __shared__ short8 As[1024], Bs[1024];          // 128 rows x 8 chunks (64 cols)
    const int tid = threadIdx.x;
    const int lane = tid & 63, wid = tid >> 6;
    const int wm = wid >> 1, wn = wid & 1;

    int sel = 0, z2v = 0;
    if constexpr (BATCH == 1) {
        int zz = blockIdx.z; sel = zz >> 6; z2v = zz & 63;
        int zb = z2v >> 4, zp = z2v & 15;
        if (sel) { A = ep.A2; Bt = ep.B2; }
        A  += (size_t)(zb * CC) * lda + zp * 128;
        Bt += (size_t)(zb * CC) * ldb + zp * 128;
    }

    int lin = blockIdx.y * gridDim.x + blockIdx.x;
    int ngw = gridDim.x * gridDim.y;
    int sw = lin;
    if (!(ngw & 7)) sw = (lin & 7) * (ngw >> 3) + (lin >> 3);
    const int m0 = (sw / gridDim.x) * 128, n0 = (sw % gridDim.x) * 128;

    const int srow = lane >> 3, schk = (lane & 7) ^ srow;
    const unsigned short* ga = A + (size_t)(m0 + wid * 32 + srow) * lda + schk * 8;
    const unsigned short* gb = Bt + (size_t)(n0 + wid * 32 + srow) * ldb + schk * 8;
    short8* lA = &As[(wid * 32) * 8];
    short8* lB = &Bs[(wid * 32) * 8];

    const int fr = lane & 15, fg = lane >> 4;

    f32x4 acc[4][4];
    #pragma unroll
    for (int i = 0; i < 4; ++i)
        #pragma unroll
        for (int j = 0; j < 4; ++j) acc[i][j] = {0.f, 0.f, 0.f, 0.f};

    for (int k0 = 0; k0 < K; k0 += 64) {
        #pragma unroll
        for (int q = 0; q < 4; ++q) {
            gl_lds16(ga + (size_t)(q * 8) * lda + k0, lA + q * 64);
            gl_lds16(gb + (size_t)(q * 8) * ldb + k0, lB + q * 64);
        }
        __syncthreads();
        #pragma unroll
        for (int kk = 0; kk < 2; ++kk) {
            short8 af[4], bf[4];
            #pragma unroll
            for (int i = 0; i < 4; ++i) {
                int ra = wm * 64 + i * 16 + fr;
                af[i] = As[ra * 8 + ((kk * 4 + fg) ^ (ra & 7))];
                int rb = wn * 64 + i * 16 + fr;
                bf[i] = Bs[rb * 8 + ((kk * 4 + fg) ^ (rb & 7))];
            }
            #pragma unroll
            for (int i = 0; i < 4; ++i)
                #pragma unroll
                for (int j = 0; j < 4; ++j)
                    acc[i][j] = __builtin_amdgcn_mfma_f32_16x16x32_bf16(af[i], bf[j], acc[i][j], 0, 0, 0);
        }
        __syncthreads();
    }

    float* gout = nullptr;
    if constexpr (EPI == 5) gout = (sel ? ep.outf2 : ep.outf) + (size_t)z2v * 65536;

    #pragma unroll
    for (int i = 0; i < 4; ++i) {
        #pragma unroll
        for (int j = 0; j < 4; ++j) {
            #pragma unroll
            for (int r = 0; r < 4; ++r) {
                int m = m0 + wm * 64 + i * 16 + fg * 4 + r;
                int n = n0 + wn * 64 + j * 16 + fr;
                float v = acc[i][j][r];
                if constexpr (EPI == 0) {
                    ep.outb[(size_t)m * ep.ldo + n] = f2bs(v);
                } else if constexpr (EPI == 3) {
                    size_t idx = (size_t)m * ep.ldo + n;
                    ep.outf[idx] = ep.addf[idx] + v;
                } else {
                    gout[(size_t)m * 256 + n] = v;
                }
            }
        }
    }
}

// ---------------------------------------------------------------------------
// Retrieval: intra-chunk decay attention + fused inter-chunk state term.
// Inter k-range split across the 4 waves with STATIC qf indexing (rule #20:
// the kc loop is fully unrolled; the wave-uniform predicate selects 2 of 8).
__global__ __launch_bounds__(256)
void attn_k(const unsigned short* __restrict__ qkv,
            const unsigned short* __restrict__ vt_s,
            const unsigned short* __restrict__ vt_f,
            const unsigned short* __restrict__ ST_s,
            const unsigned short* __restrict__ ST_f,
            const float* __restrict__ dls, const float* __restrict__ dlf,
            unsigned short* __restrict__ rcat, unsigned short* __restrict__ rfast) {
    int y = blockIdx.y;
    int qoff = y ? 768 : 0, koff = y ? 1024 : 256;
    const unsigned short* vt = y ? vt_f : vt_s;
    unsigned short* rout = y ? rfast : rcat;
    int ldr = y ? 256 : 512;
    float l2d = log2f(sigm(y ? dlf[0] : dls[0]));

    int blk = blockIdx.x;
    int b = blk >> 7;
    int t0 = (blk & 127) << 4;
    int tid = threadIdx.x;
    int lane = tid & 63, wid = tid >> 6;

    __shared__ short8 Pl[4][64];
    __shared__ float  red[16][260];

    short8 qf[8];
    const size_t rowq = (size_t)(b * TT + t0 + (lane & 15)) * 1536 + qoff + (lane >> 4) * 8;
    #pragma unroll
    for (int ch = 0; ch < 8; ++ch)
        qf[ch] = *reinterpret_cast<const short8*>(qkv + rowq + ch * 32);

    f32x4 racc[16];
    #pragma unroll
    for (int i = 0; i < 16; ++i) racc[i] = {0.f, 0.f, 0.f, 0.f};

    const int tl = (lane >> 4) * 4;

    // ---- inter-chunk term: racc = Q @ Ssuf[chunk], k-split by wave ----
    int p = (t0 >> 7) & 15;         // chunk index within batch
    if (p < 15) {
        const unsigned short* stb = (y ? ST_f : ST_s)
            + (((size_t)(b * 15 + p)) << 16)
            + (size_t)(lane & 15) * 256 + (lane >> 4) * 8;
        #pragma unroll
        for (int kc = 0; kc < 8; ++kc) {
            if ((kc >> 1) == wid) {            // wave-uniform predicate; kc STATIC
                #pragma unroll
                for (int nt = 0; nt < 16; ++nt) {
                    short8 stf = *reinterpret_cast<const short8*>(
                        stb + (size_t)nt * 16 * 256 + kc * 32);
                    racc[nt] = __builtin_amdgcn_mfma_f32_16x16x32_bf16(qf[kc], stf, racc[nt], 0, 0, 0);
                }
            }
        }
        float base = (float)(127 - ((t0 & 127) + tl));
        float rs0 = exp2f(l2d * base);
        float rs1 = exp2f(l2d * (base - 1.f));
        float rs2 = exp2f(l2d * (base - 2.f));
        float rs3 = exp2f(l2d * (base - 3.f));
        #pragma unroll
        for (int nt = 0; nt < 16; ++nt) {
            racc[nt][0] *= rs0; racc[nt][1] *= rs1;
            racc[nt][2] *= rs2; racc[nt][3] *= rs3;
        }
    }

    // ---- intra-chunk dense part ----
    unsigned short* pb = reinterpret_cast<unsigned short*>(&Pl[wid][0]);
    int sBeg = t0 & ~31;
    int sEnd = (t0 & ~127) + 128;

    for (int s0 = sBeg + wid * 32; s0 < sEnd; s0 += 128) {
        #pragma unroll
        for (int h = 0; h < 2; ++h) {
            f32x4 sacc = {0.f, 0.f, 0.f, 0.f};
            const unsigned short* kb =
                qkv + (size_t)(b * TT + s0 + h * 16 + (lane & 15)) * 1536 + koff + (lane >> 4) * 8;
            #pragma unroll
            for (int ch = 0; ch < 8; ++ch) {
                short8 kf = *reinterpret_cast<const short8*>(kb + ch * 32);
                sacc = __builtin_amdgcn_mfma_f32_16x16x32_bf16(qf[ch], kf, sacc, 0, 0, 0);
            }
            int scol = s0 + h * 16 + (lane & 15);
            #pragma unroll
            for (int r = 0; r < 4; ++r) {
                int trow = t0 + tl + r;
                int d = scol - trow;
                float w = (d > 0) ? exp2f(l2d * (float)(d - 1)) : 0.f;
                int prow = tl + r, pcol = h * 16 + (lane & 15);
                int swp = (pcol >> 3) ^ ((prow >> 1) & 3);
                pb[(prow * 4 + swp) * 8 + (pcol & 7)] = f2bs(sacc[r] * w);
            }
        }
        asm volatile("s_waitcnt lgkmcnt(0)" ::: "memory");
        __builtin_amdgcn_sched_barrier(0);
        short8 pf;
        { int prow = lane & 15; pf = Pl[wid][prow * 4 + ((lane >> 4) ^ ((prow >> 1) & 3))]; }
        const unsigned short* vb = vt + ((size_t)b * CC + (lane & 15)) * TT + s0 + (lane >> 4) * 8;
        #pragma unroll
        for (int nt = 0; nt < 16; ++nt) {
            short8 vf = *reinterpret_cast<const short8*>(vb + (size_t)nt * 16 * TT);
            racc[nt] = __builtin_amdgcn_mfma_f32_16x16x32_bf16(pf, vf, racc[nt], 0, 0, 0);
        }
    }

    for (int w = 0; w < 4; ++w) {
        if (wid == w) {
            #pragma unroll
            for (int nt = 0; nt < 16; ++nt)
                #pragma unroll
                for (int r = 0; r < 4; ++r) {
                    int row = tl + r, col = nt * 16 + (lane & 15);
                    if (w == 0) red[row][col] = racc[nt][r];
                    else        red[row][col] += racc[nt][r];
                }
        }
        __syncthreads();
    }

    {
        int row = tid >> 4, c0 = (tid & 15) * 16;
        ushort8 lo, hi;
        #pragma unroll
        for (int j = 0; j < 8; ++j) lo[j] = f2bs(red[row][c0 + j]);
        #pragma unroll
        for (int j = 0; j < 8; ++j) hi[j] = f2bs(red[row][c0 + 8 + j]);
        unsigned short* dst = rout + (size_t)(b * TT + t0 + row) * ldr + c0;
        *reinterpret_cast<ushort8*>(dst)     = lo;
        *reinterpret_cast<ushort8*>(dst + 8) = hi;
    }
}

// ---------------------------------------------------------------------------
// Elementwise suffix scan over transposed chunk states (G' = G^T layout).
__global__ void scan_states2(const float* __restrict__ Gs, const float* __restrict__ Gf,
                             const float* __restrict__ dls, const float* __restrict__ dlf,
                             unsigned short* __restrict__ STs, unsigned short* __restrict__ STf) {
    int sel = blockIdx.z;
    const float* G = sel ? Gf : Gs;
    unsigned short* ST = sel ? STf : STs;
    float d = sigm(sel ? dlf[0] : dls[0]);
    int b = blockIdx.y;
    int e0 = (blockIdx.x * 256 + threadIdx.x) * 4;
    float dL = exp2f(log2f(d) * 128.f);
    float4 s = {0.f, 0.f, 0.f, 0.f};
    for (int c = 15; c >= 1; --c) {
        float4 g = *reinterpret_cast<const float4*>(G + (((size_t)(b * 16 + c)) << 16) + e0);
        s.x = g.x + dL * s.x; s.y = g.y + dL * s.y;
        s.z = g.z + dL * s.z; s.w = g.w + dL * s.w;
        ushort4 o;
        o.x = f2bs(s.x); o.y = f2bs(s.y); o.z = f2bs(s.z); o.w = f2bs(s.w);
        *reinterpret_cast<ushort4*>(ST + (((size_t)(b * 15 + c - 1)) << 16) + e0) = o;
    }
}

// ---------------------------------------------------------------------------
extern "C" void kernel_launch(void* const* d_in, const int* in_sizes, int n_in,
                              void* d_out, int out_size, void* d_ws, size_t ws_size,
                              hipStream_t stream) {
    (void)in_sizes; (void)n_in; (void)out_size; (void)ws_size;
    const float* x          = (const float*)d_in[0];
    const float* basis_low  = (const float*)d_in[1];
    const float* basis_mid  = (const float*)d_in[2];
    const float* basis_high = (const float*)d_in[3];
    const float* slow_q = (const float*)d_in[4];
    const float* slow_k = (const float*)d_in[5];
    const float* slow_v = (const float*)d_in[6];
    const float* slow_o = (const float*)d_in[7];
    const float* slow_decay = (const float*)d_in[8];
    const float* slow_scale = (const float*)d_in[9];
    const float* fast_q = (const float*)d_in[10];
    const float* fast_k = (const float*)d_in[11];
    const float* fast_v = (const float*)d_in[12];
    const float* fast_o = (const float*)d_in[13];
    const float* fast_decay = (const float*)d_in[14];
    const float* fast_scale = (const float*)d_in[15];
    const float* low_read  = (const float*)d_in[16];
    const float* low_write = (const float*)d_in[17];
    const float* low_mix   = (const float*)d_in[18];
    const float* low_bias  = (const float*)d_in[19];
    const float* low_oscale= (const float*)d_in[20];
    const float* mid_read  = (const float*)d_in[21];
    const float* mid_write = (const float*)d_in[22];
    const float* mid_mix   = (const float*)d_in[23];
    const float* mid_bias  = (const float*)d_in[24];
    const float* mid_oscale= (const float*)d_in[25];
    const float* high_read  = (const float*)d_in[26];
    const float* high_write = (const float*)d_in[27];
    const float* high_mix   = (const float*)d_in[28];
    const float* high_bias  = (const float*)d_in[29];
    const float* high_oscale= (const float*)d_in[30];
    const float* tg_w    = (const float*)d_in[31];
    const float* tg_b    = (const float*)d_in[32];
    const float* alpha_w = (const float*)d_in[33];
    const float* alpha_b = (const float*)d_in[34];
    const float* mem_slow_scale = (const float*)d_in[35];
    const float* mem_fast_scale = (const float*)d_in[36];
    const float* op_low_scale   = (const float*)d_in[37];
    const float* op_mid_scale   = (const float*)d_in[38];
    const float* op_high_scale  = (const float*)d_in[39];
    float* out = (float*)d_out;

    char* ws = (char*)d_ws;
    size_t off = 0;
    auto alloc = [&](size_t n) { char* p = ws + off; off += (n + 255) & ~(size_t)255; return p; };
    unsigned short* WT_p1   = (unsigned short*)alloc((size_t)6 * CC * VV * 2);   // [1536][1024]
    unsigned short* WT_read = (unsigned short*)alloc((size_t)3 * CC * VV * 2);   // [768][1024]
    unsigned short* Wcat_o  = (unsigned short*)alloc((size_t)VV * 512 * 2);
    unsigned short* Wcat_w  = (unsigned short*)alloc((size_t)VV * 768 * 2);
    unsigned short* WT_mix  = (unsigned short*)alloc((size_t)3 * 65536 * 2);
    unsigned short* WT_tg   = (unsigned short*)alloc((size_t)65536 * 2);
    unsigned short* WT_al   = (unsigned short*)alloc((size_t)65536 * 2);
    unsigned short* bb_low  = (unsigned short*)alloc((size_t)VV * 32 * 2);
    unsigned short* bb_mid  = (unsigned short*)alloc((size_t)VV * 64 * 2);
    unsigned short* bb_high = (unsigned short*)alloc((size_t)VV * 128 * 2);
    unsigned short* cqkv_l  = (unsigned short*)alloc((size_t)768 * 32 * 2);
    unsigned short* cqkv_h  = (unsigned short*)alloc((size_t)768 * 128 * 2);
    unsigned short* crd_l   = (unsigned short*)alloc((size_t)256 * 32 * 2);
    unsigned short* crd_m   = (unsigned short*)alloc((size_t)256 * 64 * 2);
    unsigned short* crd_h   = (unsigned short*)alloc((size_t)256 * 128 * 2);
    unsigned short* cO_s    = (unsigned short*)alloc((size_t)256 * 32 * 2);
    unsigned short* cO_f    = (unsigned short*)alloc((size_t)256 * 128 * 2);
    unsigned short* cW_l    = (unsigned short*)alloc((size_t)256 * 32 * 2);
    unsigned short* cW_m    = (unsigned short*)alloc((size_t)256 * 64 * 2);
    unsigned short* cW_h    = (unsigned short*)alloc((size_t)256 * 128 * 2);
    unsigned short* xn      = (unsigned short*)alloc((size_t)MR * VV * 2);       // reused: Gs, ph2 xn
    unsigned short* qkv     = (unsigned short*)alloc((size_t)MR * 1536 * 2);
    unsigned short* vt_s    = (unsigned short*)alloc((size_t)BB * CC * TT * 2);
    unsigned short* vt_f    = (unsigned short*)alloc((size_t)BB * CC * TT * 2);
    unsigned short* kts_s   = (unsigned short*)alloc((size_t)BB * CC * TT * 2);
    unsigned short* kts_f   = (unsigned short*)alloc((size_t)BB * CC * TT * 2);
    unsigned short* ST_s    = (unsigned short*)alloc((size_t)BB * 15 * 65536 * 2);
    unsigned short* ST_f    = (unsigned short*)alloc((size_t)BB * 15 * 65536 * 2);
    unsigned short* rcat    = (unsigned short*)alloc((size_t)MR * 512 * 2);
    unsigned short* rfast   = (unsigned short*)alloc((size_t)MR * CC * 2);
    unsigned short* hhigh   = (unsigned short*)alloc((size_t)MR * CC * 2);
    // overlays
    float* Gs = (float*)xn;                              // 64 states fp32 = 16.7MB
    float* Gf = (float*)rcat;                            // 64 states fp32 (rcat written later)
    unsigned short* z    = qkv;
    unsigned short* hcat = qkv + (size_t)MR * 768;

    // ---- weight prep: casts ----
    {
        CastArgs ca;
        int i = 0;
        auto J = [&](const float* s, unsigned short* d, int n) { ca.j[i].src = s; ca.j[i].dst = d; ca.j[i].n = n; ++i; };
        J(basis_low,  bb_low,  VV * 32);
        J(basis_mid,  bb_mid,  VV * 64);
        J(basis_high, bb_high, VV * 128);
        J(slow_q, cqkv_l + 0 * 256 * 32, 256 * 32);
        J(slow_k, cqkv_l + 1 * 256 * 32, 256 * 32);
        J(slow_v, cqkv_l + 2 * 256 * 32, 256 * 32);
        J(fast_q, cqkv_h + 0 * 256 * 128, 256 * 128);
        J(fast_k, cqkv_h + 1 * 256 * 128, 256 * 128);
        J(fast_v, cqkv_h + 2 * 256 * 128, 256 * 128);
        J(low_read,  crd_l, 256 * 32);
        J(mid_read,  crd_m, 256 * 64);
        J(high_read, crd_h, 256 * 128);
        J(slow_o,    cO_s,  256 * 32);
        J(fast_o,    cO_f,  256 * 128);
        J(low_write, cW_l,  256 * 32);
        J(mid_write, cW_m,  256 * 64);
        J(high_write,cW_h,  256 * 128);
        cast_bf16_multi<<<dim3(17, 64), 256, 0, stream>>>(ca);
    }

    // ---- all 10 prep GEMMs in ONE launch (logits + projection weights) ----
    {
        MJobs10 js;
        auto S = [&](int i, const unsigned short* A, int lda, const unsigned short* B, int K,
                     unsigned short* o, int ldo, int gx, int nb,
                     const float* s1, const float* s2) {
            js.j[i].A = A; js.j[i].Bt = B; js.j[i].outb = o; js.j[i].s1 = s1; js.j[i].s2 = s2;
            js.j[i].lda = lda; js.j[i].ldb = K; js.j[i].K = K; js.j[i].ldo = ldo; js.j[i].gx = gx; js.j[i].nblk = nb;
        };
        S(0, cqkv_l, 32,  bb_low,  32,  WT_p1,                     VV, 16, 192, nullptr, nullptr);
        S(1, cqkv_h, 128, bb_high, 128, WT_p1 + (size_t)768 * VV,  VV, 16, 192, nullptr, nullptr);
        S(2, crd_l,  32,  bb_low,  32,  WT_read,                    VV, 16, 64, nullptr, nullptr);
        S(3, crd_m,  64,  bb_mid,  64,  WT_read + (size_t)256 * VV, VV, 16, 64, nullptr, nullptr);
        S(4, crd_h,  128, bb_high, 128, WT_read + (size_t)512 * VV, VV, 16, 64, nullptr, nullptr);
        S(5, bb_low,  32,  cO_s, 32,  Wcat_o,       512, 4, 64, slow_scale,  mem_slow_scale);
        S(6, bb_high, 128, cO_f, 128, Wcat_o + 256, 512, 4, 64, fast_scale,  mem_fast_scale);
        S(7, bb_low,  32,  cW_l, 32,  Wcat_w,       768, 4, 64, low_oscale,  op_low_scale);
        S(8, bb_mid,  64,  cW_m, 64,  Wcat_w + 256, 768, 4, 64, mid_oscale,  op_mid_scale);
        S(9, bb_high, 128, cW_h, 128, Wcat_w + 512, 768, 4, 64, high_oscale, op_high_scale);
        gemm_multi_k<<<896, 256, 0, stream>>>(js);
    }
    softmax_rows<<<576, 256, 0, stream>>>(WT_p1);    // 2304 rows, 4 rows/block

    prep_T5<<<dim3(256, 5), 256, 0, stream>>>(tg_w, alpha_w, low_mix, mid_mix, high_mix,
                                              WT_tg, WT_al, WT_mix, WT_mix + 65536, WT_mix + 131072);

    // ---- phase 1 ----
    rmsnorm_k<<<MR / 4, 256, 0, stream>>>(x, xn);
    { EpiP ep{}; ep.outb = qkv; ep.ldo = 1536;
      gemm128_k<0,0><<<dim3(12, 64), 256, 0, stream>>>(xn, 1024, WT_p1, 1024, 1024, ep); }
    transpose4_k<<<dim3(64, 8, 16), 256, 0, stream>>>(qkv, vt_s, vt_f, kts_s, kts_f, slow_decay, fast_decay);
    { EpiP ep{}; ep.outf = Gs; ep.outf2 = Gf; ep.A2 = vt_f; ep.B2 = kts_f;
      gemm128_k<5,1><<<dim3(2, 2, 128), 256, 0, stream>>>(vt_s, TT, kts_s, TT, 128, ep); }
    scan_states2<<<dim3(64, 4, 2), 256, 0, stream>>>(Gs, Gf, slow_decay, fast_decay, ST_s, ST_f);
    attn_k<<<dim3(512, 2), 256, 0, stream>>>(qkv, vt_s, vt_f, ST_s, ST_f,
                                             slow_decay, fast_decay, rcat, rfast);
    sig_k<<<dim3(4, 128), 256, 0, stream>>>(rcat, 512, WT_tg, tg_b, rfast, 256, rcat, 512, 256);
    { EpiP ep{}; ep.outf = out; ep.addf = x; ep.ldo = 1024;
      gemm128_k<3,0><<<dim3(8, 64), 256, 0, stream>>>(rcat, 512, Wcat_o, 512, 512, ep); }

    // ---- phase 2 ----
    rmsnorm_k<<<MR / 4, 256, 0, stream>>>(out, xn);
    { EpiP ep{}; ep.outb = z; ep.ldo = 768;
      gemm128_k<0,0><<<dim3(6, 64), 256, 0, stream>>>(xn, 1024, WT_read, 1024, 1024, ep); }
    gelu3_k<<<dim3(4, 128, 3), 256, 0, stream>>>(z, WT_mix, low_bias, mid_bias, high_bias, hcat, hhigh);
    sig_k<<<dim3(4, 128), 256, 0, stream>>>(hcat, 768, WT_al, alpha_b, hhigh, 256, hcat, 768, 512);
    { EpiP ep{}; ep.outf = out; ep.addf = out; ep.ldo = 1024;
      gemm128_k<3,0><<<dim3(6, 64), 256, 0, stream>>>(hcat, 768, Wcat_w, 768, 768, ep); }
}

// Round 16
// 272.006 us; speedup vs baseline: 1.0718x; 1.0482x over previous
//
#include <hip/hip_runtime.h>
#include <math.h>

#define BB 4
#define TT 2048
#define VV 1024
#define CC 256
#define MR (BB*TT)   // 8192 rows

using short8  = __attribute__((ext_vector_type(8))) short;
using ushort8 = __attribute__((ext_vector_type(8))) unsigned short;
using f32x4   = __attribute__((ext_vector_type(4))) float;

__device__ __forceinline__ float bs2f(unsigned short s) {
    return __uint_as_float(((unsigned int)s) << 16);
}
__device__ __forceinline__ unsigned short f2bs(float f) {
    unsigned int u = __float_as_uint(f);
    u += 0x7fffu + ((u >> 16) & 1u);          // round-to-nearest-even
    return (unsigned short)(u >> 16);
}
__device__ __forceinline__ void gl_lds16(const void* g, void* l) {
    __builtin_amdgcn_global_load_lds(
        (const __attribute__((address_space(1))) unsigned int*)g,
        (__attribute__((address_space(3))) unsigned int*)l, 16, 0, 0);
}
__device__ __forceinline__ float sigm(float x) { return 1.f / (1.f + expf(-x)); }
// Abramowitz-Stegun 7.1.26, |err| <= 1.5e-7
__device__ __forceinline__ float erf_f(float x) {
    float ax = fabsf(x);
    float t = 1.f / (1.f + 0.3275911f * ax);
    float p = t * (0.254829592f + t * (-0.284496736f + t * (1.421413741f +
              t * (-1.453152027f + t * 1.061405429f))));
    float e = 1.f - p * expf(-ax * ax);
    return copysignf(e, x);
}

// ---------------------------------------------------------------------------
// Fused multi-array fp32 -> bf16 cast (coalesced). grid = (njobs, 64)
struct CastJob { const float* src; unsigned short* dst; int n; };
struct CastArgs { CastJob j[17]; };

__global__ void cast_bf16_multi(CastArgs a) {
    CastJob jb = a.j[blockIdx.x];
    int off = (blockIdx.y * 256 + threadIdx.x) * 8;
    if (off + 8 > jb.n) return;
    float4 v0 = *reinterpret_cast<const float4*>(jb.src + off);
    float4 v1 = *reinterpret_cast<const float4*>(jb.src + off + 4);
    ushort8 u;
    u[0] = f2bs(v0.x); u[1] = f2bs(v0.y); u[2] = f2bs(v0.z); u[3] = f2bs(v0.w);
    u[4] = f2bs(v1.x); u[5] = f2bs(v1.y); u[6] = f2bs(v1.z); u[7] = f2bs(v1.w);
    *reinterpret_cast<ushort8*>(jb.dst + off) = u;
}

// Row softmax in place over [rows][1024] bf16, one WAVE per row (no barriers).
__global__ void softmax_rows(unsigned short* __restrict__ w) {
    int row = blockIdx.x * 4 + (threadIdx.x >> 6);
    int lane = threadIdx.x & 63;
    ushort4* rp = reinterpret_cast<ushort4*>(w + (size_t)row * 1024);
    float v[16];
    #pragma unroll
    for (int i = 0; i < 4; ++i) {
        ushort4 u = rp[lane + i * 64];
        v[i*4+0] = bs2f(u.x); v[i*4+1] = bs2f(u.y);
        v[i*4+2] = bs2f(u.z); v[i*4+3] = bs2f(u.w);
    }
    float m = v[0];
    #pragma unroll
    for (int i = 1; i < 16; ++i) m = fmaxf(m, v[i]);
    #pragma unroll
    for (int o = 32; o > 0; o >>= 1) m = fmaxf(m, __shfl_xor(m, o));
    float s = 0.f;
    #pragma unroll
    for (int i = 0; i < 16; ++i) { v[i] = expf(v[i] - m); s += v[i]; }
    #pragma unroll
    for (int o = 32; o > 0; o >>= 1) s += __shfl_xor(s, o);
    float inv = 1.f / s;
    #pragma unroll
    for (int i = 0; i < 4; ++i) {
        ushort4 u;
        u.x = f2bs(v[i*4+0] * inv); u.y = f2bs(v[i*4+1] * inv);
        u.z = f2bs(v[i*4+2] * inv); u.w = f2bs(v[i*4+3] * inv);
        rp[lane + i * 64] = u;
    }
}

// 5x fused 256x256 fp32->bf16 transpose. grid = (256,5)
__global__ void prep_T5(const float* s0, const float* s1, const float* s2,
                        const float* s3, const float* s4,
                        unsigned short* d0, unsigned short* d1, unsigned short* d2,
                        unsigned short* d3, unsigned short* d4) {
    int y = blockIdx.y;
    const float* W = y == 0 ? s0 : y == 1 ? s1 : y == 2 ? s2 : y == 3 ? s3 : s4;
    unsigned short* WT = y == 0 ? d0 : y == 1 ? d1 : y == 2 ? d2 : y == 3 ? d3 : d4;
    int n = blockIdx.x, k = threadIdx.x;
    WT[(size_t)n * 256 + k] = f2bs(W[(size_t)k * 256 + n]);
}

// ---------------------------------------------------------------------------
// RMS norm: one WAVE per row (V=1024), 4 rows/block, no barriers. grid = MR/4.
__global__ void rmsnorm_k(const float* __restrict__ x, unsigned short* __restrict__ xn) {
    int row = blockIdx.x * 4 + (threadIdx.x >> 6);
    int lane = threadIdx.x & 63;
    const float4* src = reinterpret_cast<const float4*>(x + (size_t)row * VV);
    float4 v[4];
    float s = 0.f;
    #pragma unroll
    for (int i = 0; i < 4; ++i) {
        v[i] = src[lane + i * 64];
        s += v[i].x*v[i].x + v[i].y*v[i].y + v[i].z*v[i].z + v[i].w*v[i].w;
    }
    #pragma unroll
    for (int o = 32; o > 0; o >>= 1) s += __shfl_xor(s, o);
    float r = rsqrtf(s * (1.f / VV) + 1.1920929e-7f);
    ushort4* dst = reinterpret_cast<ushort4*>(xn + (size_t)row * VV);
    #pragma unroll
    for (int i = 0; i < 4; ++i) {
        ushort4 u;
        u.x = f2bs(v[i].x * r); u.y = f2bs(v[i].y * r);
        u.z = f2bs(v[i].z * r); u.w = f2bs(v[i].w * r);
        dst[lane + i * 64] = u;
    }
}

// ---------------------------------------------------------------------------
// 4-in-1 bf16 transpose of qkv slices: V^T (plain) and K^T (decay-scaled).
// grid (64, 8, 16): z -> (which = z>>2, b = z&3)
__global__ void transpose4_k(const unsigned short* __restrict__ qkv,
                             unsigned short* __restrict__ vt_s,
                             unsigned short* __restrict__ vt_f,
                             unsigned short* __restrict__ kts_s,
                             unsigned short* __restrict__ kts_f,
                             const float* __restrict__ dls,
                             const float* __restrict__ dlf) {
    __shared__ unsigned short tile[32][33];
    int z = blockIdx.z, b = z & 3, which = z >> 2;
    int srcoff = which == 0 ? 512 : which == 1 ? 1280 : which == 2 ? 256 : 1024;
    unsigned short* dst = which == 0 ? vt_s : which == 1 ? vt_f : which == 2 ? kts_s : kts_f;
    float l2d = 0.f;
    if (which == 2) l2d = log2f(sigm(dls[0]));
    if (which == 3) l2d = log2f(sigm(dlf[0]));
    int t0 = blockIdx.x * 32, c0 = blockIdx.y * 32;
    int tx = threadIdx.x & 31, ty = threadIdx.x >> 5;
    const unsigned short* src = qkv + srcoff;
    #pragma unroll
    for (int i = 0; i < 4; ++i) {
        int r = ty + i * 8;
        tile[r][tx] = src[(size_t)(b * TT + t0 + r) * 1536 + c0 + tx];
    }
    __syncthreads();
    float w = (which >= 2) ? exp2f(l2d * (float)((t0 + tx) & 127)) : 1.f;
    #pragma unroll
    for (int i = 0; i < 4; ++i) {
        int r = ty + i * 8;
        dst[((size_t)b * CC + c0 + r) * TT + t0 + tx] = f2bs(bs2f(tile[tx][r]) * w);
    }
}

// ---------------------------------------------------------------------------
// Shared 64x64 GEMM core
__device__ __forceinline__ void gemm64_core(
    const unsigned short* A, int lda, const unsigned short* Bt, int ldb,
    int K, int m0, int n0, short8* As, short8* Bs, f32x4 (&acc)[2][2]) {
    const int tid = threadIdx.x;
    const int lane = tid & 63, wid = tid >> 6;
    const int wm = wid >> 1, wn = wid & 1;
    const int lrow = tid >> 2, lch = tid & 3;
    const int sws = lch ^ ((lrow >> 1) & 3);
    const unsigned short* ag = A + (size_t)(m0 + lrow) * lda + lch * 8;
    const unsigned short* bg = Bt + (size_t)(n0 + lrow) * ldb + lch * 8;
    #pragma unroll
    for (int i = 0; i < 2; ++i)
        #pragma unroll
        for (int j = 0; j < 2; ++j) acc[i][j] = {0.f, 0.f, 0.f, 0.f};
    const int g = lane >> 4;
    const int ra0 = wm * 32 + (lane & 15);
    const int rb0 = wn * 32 + (lane & 15);
    for (int k0 = 0; k0 < K; k0 += 32) {
        As[lrow * 4 + sws] = *reinterpret_cast<const short8*>(ag + k0);
        Bs[lrow * 4 + sws] = *reinterpret_cast<const short8*>(bg + k0);
        __syncthreads();
        short8 af[2], bf[2];
        #pragma unroll
        for (int i = 0; i < 2; ++i) {
            int ra = ra0 + i * 16;
            af[i] = As[ra * 4 + (g ^ ((ra >> 1) & 3))];
            int rb = rb0 + i * 16;
            bf[i] = Bs[rb * 4 + (g ^ ((rb >> 1) & 3))];
        }
        #pragma unroll
        for (int i = 0; i < 2; ++i)
            #pragma unroll
            for (int j = 0; j < 2; ++j)
                acc[i][j] = __builtin_amdgcn_mfma_f32_16x16x32_bf16(af[i], bf[j], acc[i][j], 0, 0, 0);
        __syncthreads();
    }
}

#define EPI_LOOP(MV, NV, VV_, BODY)                                            \
    {   const int lane_ = threadIdx.x & 63, wid_ = threadIdx.x >> 6;           \
        const int wm_ = wid_ >> 1, wn_ = wid_ & 1;                             \
        _Pragma("unroll")                                                      \
        for (int i_ = 0; i_ < 2; ++i_)                                         \
        { _Pragma("unroll")                                                    \
          for (int j_ = 0; j_ < 2; ++j_)                                       \
          { _Pragma("unroll")                                                  \
            for (int r_ = 0; r_ < 4; ++r_)                                     \
            { int MV = m0 + wm_ * 32 + i_ * 16 + (lane_ >> 4) * 4 + r_;        \
              int NV = n0 + wn_ * 32 + j_ * 16 + (lane_ & 15);                 \
              float VV_ = acc[i_][j_][r_];                                     \
              BODY } } } }

// ---------------------------------------------------------------------------
// Multi-job 64^2 GEMM (10 jobs, 1 launch). scale = s1*s2 (or 1 if s1==null).
struct MJob {
    const unsigned short* A; const unsigned short* Bt; unsigned short* outb;
    const float* s1; const float* s2;
    int lda, ldb, K, ldo, gx, nblk;
};
struct MJobs10 { MJob j[10]; };

__global__ __launch_bounds__(256)
void gemm_multi_k(MJobs10 js) {
    int bid = blockIdx.x, ji = 0, base = 0;
    while (bid >= base + js.j[ji].nblk) { base += js.j[ji].nblk; ++ji; }
    MJob jb = js.j[ji];
    int rem = bid - base;
    int m0 = (rem / jb.gx) * 64, n0 = (rem % jb.gx) * 64;
    __shared__ short8 As[256], Bs[256];
    f32x4 acc[2][2];
    gemm64_core(jb.A, jb.lda, jb.Bt, jb.ldb, jb.K, m0, n0, As, Bs, acc);
    float sc = jb.s1 ? jb.s1[0] * jb.s2[0] : 1.f;
    EPI_LOOP(m, n, v, { jb.outb[(size_t)m * jb.ldo + n] = f2bs(v * sc); })
}

// sigmoid(acc+bias)*aux epilogue GEMM (K=256, ldb=256). grid (4,128)
__global__ __launch_bounds__(256)
void sig_k(const unsigned short* A, int lda, const unsigned short* Bt,
           const float* bias, const unsigned short* aux, int ldaux,
           unsigned short* outb, int ldo, int coloff) {
    int m0 = blockIdx.y * 64, n0 = blockIdx.x * 64;
    __shared__ short8 As[256], Bs[256];
    f32x4 acc[2][2];
    gemm64_core(A, lda, Bt, 256, 256, m0, n0, As, Bs, acc);
    EPI_LOOP(m, n, v, {
        float s = sigm(v + bias[n]);
        float a = bs2f(aux[(size_t)m * ldaux + n]);
        outb[(size_t)m * ldo + coloff + n] = f2bs(s * a);
    })
}

// 3x gelu(z@mix+bias) batched over z. grid (4,128,3)
__global__ __launch_bounds__(256)
void gelu3_k(const unsigned short* zbuf, const unsigned short* WT_mix,
             const float* lb, const float* mb, const float* hb,
             unsigned short* hcat, unsigned short* hhigh) {
    int zi = blockIdx.z;
    const unsigned short* A = zbuf + zi * 256;
    const unsigned short* Bt = WT_mix + (size_t)zi * 65536;
    const float* bias = zi == 0 ? lb : zi == 1 ? mb : hb;
    unsigned short* outb = zi == 2 ? hhigh : hcat;
    int ldo = zi == 2 ? 256 : 768;
    int coloff = zi == 1 ? 256 : 0;
    int m0 = blockIdx.y * 64, n0 = blockIdx.x * 64;
    __shared__ short8 As[256], Bs[256];
    f32x4 acc[2][2];
    gemm64_core(A, 768, Bt, 256, 256, m0, n0, As, Bs, acc);
    EPI_LOOP(m, n, v, {
        float z = v + bias[n];
        float h = 0.5f * z * (1.f + erf_f(z * 0.70710678118654752f));
        outb[(size_t)m * ldo + coloff + n] = f2bs(h);
    })
}

// ---------------------------------------------------------------------------
// 128x128 GEMM, BK=64, single-buffer global_load_lds, XCD swizzle (ngw%8==0).
// EPI: 0 bf16 store | 3 fp32 out=addf+acc | 5 f32 store (gstate) | 6 decay-RMW
// BATCH: 0 plain | 1 gstate (z = sel*64+b*16+chunk) | 2 inter (z = sel*60+b*15+p)
struct EpiP {
    float* outf; const float* addf;
    unsigned short* outb; int ldo;
    const unsigned short* A2; const unsigned short* B2;
    float* outf2;
    unsigned short* outb2; int ldo2;
    const float* dls; const float* dlf;
};

template<int EPI, int BATCH>
__global__ __launch_bounds__(256)
void gemm128_k(const unsigned short* __restrict__ A, int lda,
               const unsigned short* __restrict__ Bt, int ldb, int K, EpiP ep) {
    __shared__ short8 As[1024], Bs[1024];          // 128 rows x 8 chunks (64 cols)
    const int tid = threadIdx.x;
    const int lane = tid & 63, wid = tid >> 6;
    const int wm = wid >> 1, wn = wid & 1;

    int sel = 0, z2v = 0, zb = 0, zp = 0;
    if constexpr (BATCH == 1) {
        int zz = blockIdx.z; sel = zz >> 6; z2v = zz & 63;
        zb = z2v >> 4; zp = z2v & 15;
        if (sel) { A = ep.A2; Bt = ep.B2; }
        A  += (size_t)(zb * CC) * lda + zp * 128;
        Bt += (size_t)(zb * CC) * ldb + zp * 128;
    } else if constexpr (BATCH == 2) {
        int zz = blockIdx.z; sel = zz >= 60 ? 1 : 0; z2v = sel ? zz - 60 : zz;
        zb = z2v / 15; zp = z2v % 15;
        if (sel) Bt = ep.B2;
        A  += (sel ? 768 : 0) + (size_t)(zb * TT + zp * 128) * lda;
        Bt += (size_t)z2v * 65536;
    }

    int lin = blockIdx.y * gridDim.x + blockIdx.x;
    int ngw = gridDim.x * gridDim.y;
    int sw = lin;
    if (!(ngw & 7)) sw = (lin & 7) * (ngw >> 3) + (lin >> 3);
    const int m0 = (sw / gridDim.x) * 128, n0 = (sw % gridDim.x) * 128;

    const int srow = lane >> 3, schk = (lane & 7) ^ srow;
    const unsigned short* ga = A + (size_t)(m0 + wid * 32 + srow) * lda + schk * 8;
    const unsigned short* gb = Bt + (size_t)(n0 + wid * 32 + srow) * ldb + schk * 8;
    short8* lA = &As[(wid * 32) * 8];
    short8* lB = &Bs[(wid * 32) * 8];

    const int fr = lane & 15, fg = lane >> 4;

    f32x4 acc[4][4];
    #pragma unroll
    for (int i = 0; i < 4; ++i)
        #pragma unroll
        for (int j = 0; j < 4; ++j) acc[i][j] = {0.f, 0.f, 0.f, 0.f};

    for (int k0 = 0; k0 < K; k0 += 64) {
        #pragma unroll
        for (int q = 0; q < 4; ++q) {
            gl_lds16(ga + (size_t)(q * 8) * lda + k0, lA + q * 64);
            gl_lds16(gb + (size_t)(q * 8) * ldb + k0, lB + q * 64);
        }
        __syncthreads();
        #pragma unroll
        for (int kk = 0; kk < 2; ++kk) {
            short8 af[4], bf[4];
            #pragma unroll
            for (int i = 0; i < 4; ++i) {
                int ra = wm * 64 + i * 16 + fr;
                af[i] = As[ra * 8 + ((kk * 4 + fg) ^ (ra & 7))];
                int rb = wn * 64 + i * 16 + fr;
                bf[i] = Bs[rb * 8 + ((kk * 4 + fg) ^ (rb & 7))];
            }
            #pragma unroll
            for (int i = 0; i < 4; ++i)
                #pragma unroll
                for (int j = 0; j < 4; ++j)
                    acc[i][j] = __builtin_amdgcn_mfma_f32_16x16x32_bf16(af[i], bf[j], acc[i][j], 0, 0, 0);
        }
        __syncthreads();
    }

    float l2d6 = 0.f;
    if constexpr (EPI == 6) l2d6 = log2f(sigm(sel ? ep.dlf[0] : ep.dls[0]));
    unsigned short* ob = ep.outb;
    int ldo = ep.ldo;
    if constexpr (EPI == 6) { if (sel) { ob = ep.outb2; ldo = ep.ldo2; } }
    float* gout = nullptr;
    if constexpr (EPI == 5) gout = (sel ? ep.outf2 : ep.outf) + (size_t)z2v * 65536;

    #pragma unroll
    for (int i = 0; i < 4; ++i) {
        #pragma unroll
        for (int j = 0; j < 4; ++j) {
            #pragma unroll
            for (int r = 0; r < 4; ++r) {
                int m = m0 + wm * 64 + i * 16 + fg * 4 + r;
                int n = n0 + wn * 64 + j * 16 + fr;
                float v = acc[i][j][r];
                if constexpr (EPI == 0) {
                    ob[(size_t)m * ldo + n] = f2bs(v);
                } else if constexpr (EPI == 3) {
                    size_t idx = (size_t)m * ep.ldo + n;
                    ep.outf[idx] = ep.addf[idx] + v;
                } else if constexpr (EPI == 5) {
                    gout[(size_t)m * 256 + n] = v;
                } else if constexpr (EPI == 6) {
                    float rs = exp2f(l2d6 * (float)(127 - m));
                    size_t idx = (size_t)(zb * TT + zp * 128 + m) * ldo + n;
                    ob[idx] = f2bs(bs2f(ob[idx]) + v * rs);
                }
            }
        }
    }
}

// ---------------------------------------------------------------------------
// Intra-chunk decay retrieval; slow (y=0) and fast (y=1) merged in one grid.
__global__ __launch_bounds__(256)
void attn_k(const unsigned short* __restrict__ qkv,
            const unsigned short* __restrict__ vt_s,
            const unsigned short* __restrict__ vt_f,
            const float* __restrict__ dls, const float* __restrict__ dlf,
            unsigned short* __restrict__ rcat, unsigned short* __restrict__ rfast) {
    int y = blockIdx.y;
    int qoff = y ? 768 : 0, koff = y ? 1024 : 256;
    const unsigned short* vt = y ? vt_f : vt_s;
    unsigned short* rout = y ? rfast : rcat;
    int ldr = y ? 256 : 512;
    float l2d = log2f(sigm(y ? dlf[0] : dls[0]));

    int blk = blockIdx.x;
    int b = blk >> 7;
    int t0 = (blk & 127) << 4;
    int tid = threadIdx.x;
    int lane = tid & 63, wid = tid >> 6;

    __shared__ short8 Pl[4][64];
    __shared__ float  red[16][260];

    short8 qf[8];
    const size_t rowq = (size_t)(b * TT + t0 + (lane & 15)) * 1536 + qoff + (lane >> 4) * 8;
    #pragma unroll
    for (int ch = 0; ch < 8; ++ch)
        qf[ch] = *reinterpret_cast<const short8*>(qkv + rowq + ch * 32);

    f32x4 racc[16];
    #pragma unroll
    for (int i = 0; i < 16; ++i) racc[i] = {0.f, 0.f, 0.f, 0.f};

    unsigned short* pb = reinterpret_cast<unsigned short*>(&Pl[wid][0]);

    int sBeg = t0 & ~31;
    int sEnd = (t0 & ~127) + 128;
    const int tl = (lane >> 4) * 4;

    for (int s0 = sBeg + wid * 32; s0 < sEnd; s0 += 128) {
        #pragma unroll
        for (int h = 0; h < 2; ++h) {
            f32x4 sacc = {0.f, 0.f, 0.f, 0.f};
            const unsigned short* kb =
                qkv + (size_t)(b * TT + s0 + h * 16 + (lane & 15)) * 1536 + koff + (lane >> 4) * 8;
            #pragma unroll
            for (int ch = 0; ch < 8; ++ch) {
                short8 kf = *reinterpret_cast<const short8*>(kb + ch * 32);
                sacc = __builtin_amdgcn_mfma_f32_16x16x32_bf16(qf[ch], kf, sacc, 0, 0, 0);
            }
            int scol = s0 + h * 16 + (lane & 15);
            #pragma unroll
            for (int r = 0; r < 4; ++r) {
                int trow = t0 + tl + r;
                int d = scol - trow;
                float w = (d > 0) ? exp2f(l2d * (float)(d - 1)) : 0.f;
                int prow = tl + r, pcol = h * 16 + (lane & 15);
                int swp = (pcol >> 3) ^ ((prow >> 1) & 3);
                pb[(prow * 4 + swp) * 8 + (pcol & 7)] = f2bs(sacc[r] * w);
            }
        }
        asm volatile("s_waitcnt lgkmcnt(0)" ::: "memory");
        __builtin_amdgcn_sched_barrier(0);
        short8 pf;
        { int prow = lane & 15; pf = Pl[wid][prow * 4 + ((lane >> 4) ^ ((prow >> 1) & 3))]; }
        const unsigned short* vb = vt + ((size_t)b * CC + (lane & 15)) * TT + s0 + (lane >> 4) * 8;
        #pragma unroll
        for (int nt = 0; nt < 16; ++nt) {
            short8 vf = *reinterpret_cast<const short8*>(vb + (size_t)nt * 16 * TT);
            racc[nt] = __builtin_amdgcn_mfma_f32_16x16x32_bf16(pf, vf, racc[nt], 0, 0, 0);
        }
    }

    for (int w = 0; w < 4; ++w) {
        if (wid == w) {
            #pragma unroll
            for (int nt = 0; nt < 16; ++nt)
                #pragma unroll
                for (int r = 0; r < 4; ++r) {
                    int row = tl + r, col = nt * 16 + (lane & 15);
                    if (w == 0) red[row][col] = racc[nt][r];
                    else        red[row][col] += racc[nt][r];
                }
        }
        __syncthreads();
    }

    {
        int row = tid >> 4, c0 = (tid & 15) * 16;
        ushort8 lo, hi;
        #pragma unroll
        for (int j = 0; j < 8; ++j) lo[j] = f2bs(red[row][c0 + j]);
        #pragma unroll
        for (int j = 0; j < 8; ++j) hi[j] = f2bs(red[row][c0 + 8 + j]);
        unsigned short* dst = rout + (size_t)(b * TT + t0 + row) * ldr + c0;
        *reinterpret_cast<ushort8*>(dst)     = lo;
        *reinterpret_cast<ushort8*>(dst + 8) = hi;
    }
}

// ---------------------------------------------------------------------------
// Elementwise suffix scan over transposed chunk states (G' = G^T layout).
__global__ void scan_states2(const float* __restrict__ Gs, const float* __restrict__ Gf,
                             const float* __restrict__ dls, const float* __restrict__ dlf,
                             unsigned short* __restrict__ STs, unsigned short* __restrict__ STf) {
    int sel = blockIdx.z;
    const float* G = sel ? Gf : Gs;
    unsigned short* ST = sel ? STf : STs;
    float d = sigm(sel ? dlf[0] : dls[0]);
    int b = blockIdx.y;
    int e0 = (blockIdx.x * 256 + threadIdx.x) * 4;
    float dL = exp2f(log2f(d) * 128.f);
    float4 s = {0.f, 0.f, 0.f, 0.f};
    for (int c = 15; c >= 1; --c) {
        float4 g = *reinterpret_cast<const float4*>(G + (((size_t)(b * 16 + c)) << 16) + e0);
        s.x = g.x + dL * s.x; s.y = g.y + dL * s.y;
        s.z = g.z + dL * s.z; s.w = g.w + dL * s.w;
        ushort4 o;
        o.x = f2bs(s.x); o.y = f2bs(s.y); o.z = f2bs(s.z); o.w = f2bs(s.w);
        *reinterpret_cast<ushort4*>(ST + (((size_t)(b * 15 + c - 1)) << 16) + e0) = o;
    }
}

// ---------------------------------------------------------------------------
extern "C" void kernel_launch(void* const* d_in, const int* in_sizes, int n_in,
                              void* d_out, int out_size, void* d_ws, size_t ws_size,
                              hipStream_t stream) {
    (void)in_sizes; (void)n_in; (void)out_size; (void)ws_size;
    const float* x          = (const float*)d_in[0];
    const float* basis_low  = (const float*)d_in[1];
    const float* basis_mid  = (const float*)d_in[2];
    const float* basis_high = (const float*)d_in[3];
    const float* slow_q = (const float*)d_in[4];
    const float* slow_k = (const float*)d_in[5];
    const float* slow_v = (const float*)d_in[6];
    const float* slow_o = (const float*)d_in[7];
    const float* slow_decay = (const float*)d_in[8];
    const float* slow_scale = (const float*)d_in[9];
    const float* fast_q = (const float*)d_in[10];
    const float* fast_k = (const float*)d_in[11];
    const float* fast_v = (const float*)d_in[12];
    const float* fast_o = (const float*)d_in[13];
    const float* fast_decay = (const float*)d_in[14];
    const float* fast_scale = (const float*)d_in[15];
    const float* low_read  = (const float*)d_in[16];
    const float* low_write = (const float*)d_in[17];
    const float* low_mix   = (const float*)d_in[18];
    const float* low_bias  = (const float*)d_in[19];
    const float* low_oscale= (const float*)d_in[20];
    const float* mid_read  = (const float*)d_in[21];
    const float* mid_write = (const float*)d_in[22];
    const float* mid_mix   = (const float*)d_in[23];
    const float* mid_bias  = (const float*)d_in[24];
    const float* mid_oscale= (const float*)d_in[25];
    const float* high_read  = (const float*)d_in[26];
    const float* high_write = (const float*)d_in[27];
    const float* high_mix   = (const float*)d_in[28];
    const float* high_bias  = (const float*)d_in[29];
    const float* high_oscale= (const float*)d_in[30];
    const float* tg_w    = (const float*)d_in[31];
    const float* tg_b    = (const float*)d_in[32];
    const float* alpha_w = (const float*)d_in[33];
    const float* alpha_b = (const float*)d_in[34];
    const float* mem_slow_scale = (const float*)d_in[35];
    const float* mem_fast_scale = (const float*)d_in[36];
    const float* op_low_scale   = (const float*)d_in[37];
    const float* op_mid_scale   = (const float*)d_in[38];
    const float* op_high_scale  = (const float*)d_in[39];
    float* out = (float*)d_out;

    char* ws = (char*)d_ws;
    size_t off = 0;
    auto alloc = [&](size_t n) { char* p = ws + off; off += (n + 255) & ~(size_t)255; return p; };
    unsigned short* WT_p1   = (unsigned short*)alloc((size_t)6 * CC * VV * 2);   // [1536][1024]
    unsigned short* WT_read = (unsigned short*)alloc((size_t)3 * CC * VV * 2);   // [768][1024]
    unsigned short* Wcat_o  = (unsigned short*)alloc((size_t)VV * 512 * 2);
    unsigned short* Wcat_w  = (unsigned short*)alloc((size_t)VV * 768 * 2);
    unsigned short* WT_mix  = (unsigned short*)alloc((size_t)3 * 65536 * 2);
    unsigned short* WT_tg   = (unsigned short*)alloc((size_t)65536 * 2);
    unsigned short* WT_al   = (unsigned short*)alloc((size_t)65536 * 2);
    unsigned short* bb_low  = (unsigned short*)alloc((size_t)VV * 32 * 2);
    unsigned short* bb_mid  = (unsigned short*)alloc((size_t)VV * 64 * 2);
    unsigned short* bb_high = (unsigned short*)alloc((size_t)VV * 128 * 2);
    unsigned short* cqkv_l  = (unsigned short*)alloc((size_t)768 * 32 * 2);
    unsigned short* cqkv_h  = (unsigned short*)alloc((size_t)768 * 128 * 2);
    unsigned short* crd_l   = (unsigned short*)alloc((size_t)256 * 32 * 2);
    unsigned short* crd_m   = (unsigned short*)alloc((size_t)256 * 64 * 2);
    unsigned short* crd_h   = (unsigned short*)alloc((size_t)256 * 128 * 2);
    unsigned short* cO_s    = (unsigned short*)alloc((size_t)256 * 32 * 2);
    unsigned short* cO_f    = (unsigned short*)alloc((size_t)256 * 128 * 2);
    unsigned short* cW_l    = (unsigned short*)alloc((size_t)256 * 32 * 2);
    unsigned short* cW_m    = (unsigned short*)alloc((size_t)256 * 64 * 2);
    unsigned short* cW_h    = (unsigned short*)alloc((size_t)256 * 128 * 2);
    unsigned short* xn      = (unsigned short*)alloc((size_t)MR * VV * 2);       // reused: Gs, ph2 xn
    unsigned short* qkv     = (unsigned short*)alloc((size_t)MR * 1536 * 2);
    unsigned short* vt_s    = (unsigned short*)alloc((size_t)BB * CC * TT * 2);
    unsigned short* vt_f    = (unsigned short*)alloc((size_t)BB * CC * TT * 2);
    unsigned short* kts_s   = (unsigned short*)alloc((size_t)BB * CC * TT * 2);
    unsigned short* kts_f   = (unsigned short*)alloc((size_t)BB * CC * TT * 2);
    unsigned short* ST_s    = (unsigned short*)alloc((size_t)BB * 15 * 65536 * 2);
    unsigned short* ST_f    = (unsigned short*)alloc((size_t)BB * 15 * 65536 * 2);
    unsigned short* rcat    = (unsigned short*)alloc((size_t)MR * 512 * 2);
    unsigned short* rfast   = (unsigned short*)alloc((size_t)MR * CC * 2);
    unsigned short* hhigh   = (unsigned short*)alloc((size_t)MR * CC * 2);
    // overlays
    float* Gs = (float*)xn;                              // 64 states fp32 = 16.7MB
    float* Gf = (float*)rcat;                            // 64 states fp32 (rcat written later)
    unsigned short* z    = qkv;
    unsigned short* hcat = qkv + (size_t)MR * 768;

    // ---- weight prep: casts ----
    {
        CastArgs ca;
        int i = 0;
        auto J = [&](const float* s, unsigned short* d, int n) { ca.j[i].src = s; ca.j[i].dst = d; ca.j[i].n = n; ++i; };
        J(basis_low,  bb_low,  VV * 32);
        J(basis_mid,  bb_mid,  VV * 64);
        J(basis_high, bb_high, VV * 128);
        J(slow_q, cqkv_l + 0 * 256 * 32, 256 * 32);
        J(slow_k, cqkv_l + 1 * 256 * 32, 256 * 32);
        J(slow_v, cqkv_l + 2 * 256 * 32, 256 * 32);
        J(fast_q, cqkv_h + 0 * 256 * 128, 256 * 128);
        J(fast_k, cqkv_h + 1 * 256 * 128, 256 * 128);
        J(fast_v, cqkv_h + 2 * 256 * 128, 256 * 128);
        J(low_read,  crd_l, 256 * 32);
        J(mid_read,  crd_m, 256 * 64);
        J(high_read, crd_h, 256 * 128);
        J(slow_o,    cO_s,  256 * 32);
        J(fast_o,    cO_f,  256 * 128);
        J(low_write, cW_l,  256 * 32);
        J(mid_write, cW_m,  256 * 64);
        J(high_write,cW_h,  256 * 128);
        cast_bf16_multi<<<dim3(17, 64), 256, 0, stream>>>(ca);
    }

    // ---- all 10 prep GEMMs in ONE launch (logits + projection weights) ----
    {
        MJobs10 js;
        auto S = [&](int i, const unsigned short* A, int lda, const unsigned short* B, int K,
                     unsigned short* o, int ldo, int gx, int nb,
                     const float* s1, const float* s2) {
            js.j[i].A = A; js.j[i].Bt = B; js.j[i].outb = o; js.j[i].s1 = s1; js.j[i].s2 = s2;
            js.j[i].lda = lda; js.j[i].ldb = K; js.j[i].K = K; js.j[i].ldo = ldo; js.j[i].gx = gx; js.j[i].nblk = nb;
        };
        S(0, cqkv_l, 32,  bb_low,  32,  WT_p1,                     VV, 16, 192, nullptr, nullptr);
        S(1, cqkv_h, 128, bb_high, 128, WT_p1 + (size_t)768 * VV,  VV, 16, 192, nullptr, nullptr);
        S(2, crd_l,  32,  bb_low,  32,  WT_read,                    VV, 16, 64, nullptr, nullptr);
        S(3, crd_m,  64,  bb_mid,  64,  WT_read + (size_t)256 * VV, VV, 16, 64, nullptr, nullptr);
        S(4, crd_h,  128, bb_high, 128, WT_read + (size_t)512 * VV, VV, 16, 64, nullptr, nullptr);
        S(5, bb_low,  32,  cO_s, 32,  Wcat_o,       512, 4, 64, slow_scale,  mem_slow_scale);
        S(6, bb_high, 128, cO_f, 128, Wcat_o + 256, 512, 4, 64, fast_scale,  mem_fast_scale);
        S(7, bb_low,  32,  cW_l, 32,  Wcat_w,       768, 4, 64, low_oscale,  op_low_scale);
        S(8, bb_mid,  64,  cW_m, 64,  Wcat_w + 256, 768, 4, 64, mid_oscale,  op_mid_scale);
        S(9, bb_high, 128, cW_h, 128, Wcat_w + 512, 768, 4, 64, high_oscale, op_high_scale);
        gemm_multi_k<<<896, 256, 0, stream>>>(js);
    }
    softmax_rows<<<576, 256, 0, stream>>>(WT_p1);    // 2304 rows, 4 rows/block

    prep_T5<<<dim3(256, 5), 256, 0, stream>>>(tg_w, alpha_w, low_mix, mid_mix, high_mix,
                                              WT_tg, WT_al, WT_mix, WT_mix + 65536, WT_mix + 131072);

    // ---- phase 1 ----
    rmsnorm_k<<<MR / 4, 256, 0, stream>>>(x, xn);
    { EpiP ep{}; ep.outb = qkv; ep.ldo = 1536;
      gemm128_k<0,0><<<dim3(12, 64), 256, 0, stream>>>(xn, 1024, WT_p1, 1024, 1024, ep); }
    transpose4_k<<<dim3(64, 8, 16), 256, 0, stream>>>(qkv, vt_s, vt_f, kts_s, kts_f, slow_decay, fast_decay);
    { EpiP ep{}; ep.outf = Gs; ep.outf2 = Gf; ep.A2 = vt_f; ep.B2 = kts_f;
      gemm128_k<5,1><<<dim3(2, 2, 128), 256, 0, stream>>>(vt_s, TT, kts_s, TT, 128, ep); }
    scan_states2<<<dim3(64, 4, 2), 256, 0, stream>>>(Gs, Gf, slow_decay, fast_decay, ST_s, ST_f);
    attn_k<<<dim3(512, 2), 256, 0, stream>>>(qkv, vt_s, vt_f, slow_decay, fast_decay, rcat, rfast);
    { EpiP ep{}; ep.outb = rcat; ep.ldo = 512; ep.outb2 = rfast; ep.ldo2 = 256;
      ep.dls = slow_decay; ep.dlf = fast_decay; ep.B2 = ST_f;
      gemm128_k<6,2><<<dim3(2, 1, 120), 256, 0, stream>>>(qkv, 1536, ST_s, 256, 256, ep); }
    sig_k<<<dim3(4, 128), 256, 0, stream>>>(rcat, 512, WT_tg, tg_b, rfast, 256, rcat, 512, 256);
    { EpiP ep{}; ep.outf = out; ep.addf = x; ep.ldo = 1024;
      gemm128_k<3,0><<<dim3(8, 64), 256, 0, stream>>>(rcat, 512, Wcat_o, 512, 512, ep); }

    // ---- phase 2 ----
    rmsnorm_k<<<MR / 4, 256, 0, stream>>>(out, xn);
    { EpiP ep{}; ep.outb = z; ep.ldo = 768;
      gemm128_k<0,0><<<dim3(6, 64), 256, 0, stream>>>(xn, 1024, WT_read, 1024, 1024, ep); }
    gelu3_k<<<dim3(4, 128, 3), 256, 0, stream>>>(z, WT_mix, low_bias, mid_bias, high_bias, hcat, hhigh);
    sig_k<<<dim3(4, 128), 256, 0, stream>>>(hcat, 768, WT_al, alpha_b, hhigh, 256, hcat, 768, 512);
    { EpiP ep{}; ep.outf = out; ep.addf = out; ep.ldo = 1024;
      gemm128_k<3,0><<<dim3(6, 64), 256, 0, stream>>>(hcat, 768, Wcat_w, 768, 768, ep); }
}